// Round 11
// baseline (1430.374 us; speedup 1.0000x reference)
//
#include <hip/hip_runtime.h>

using bf16   = __bf16;
using bf16x8 = __bf16 __attribute__((ext_vector_type(8)));
using f32x4  = float  __attribute__((ext_vector_type(4)));

// B=1024, T=64, F=256, H=1024, C=2
// ws layout: identical to R7.

__device__ __forceinline__ float sigm(float x) { return 1.f / (1.f + __expf(-x)); }
__device__ __forceinline__ float tanh_fast(float x) {
  float e = __expf(2.f * x);
  return 1.f - 2.f / (e + 1.f);
}

#define GLL16(gsrc, ldst)                                                              \
  __builtin_amdgcn_global_load_lds((const __attribute__((address_space(1))) void*)(gsrc), \
                                   (__attribute__((address_space(3))) void*)(ldst), 16, 0, 0)

// ---------------------------------------------------------------------------
// prep: pre-swizzled XRs ([xr|m], f XOR (b&7)<<3) and Dbfs
// ---------------------------------------------------------------------------
__global__ void prep_kernel(const float* __restrict__ X, const float* __restrict__ Msk,
                            const float* __restrict__ D, const float* __restrict__ Mean,
                            const float* __restrict__ L, const float* __restrict__ w_gx,
                            const float* __restrict__ b_gx,
                            bf16* __restrict__ XRs, bf16* __restrict__ Dbfs,
                            int c, int nsl) {
  int i = blockIdx.x * 256 + threadIdx.x;
  if (i >= (nsl << 18)) return;
  int f = i & 255, b = (i >> 8) & 1023, tl = i >> 18;
  int t = c * 16 + tl;
  size_t g = ((size_t)b << 14) + ((size_t)t << 8) + f;
  float d = D[g];
  int fs = f ^ ((b & 7) << 3);
  int row = tl * 1024 + b;
  Dbfs[(size_t)row * 256 + fs] = (bf16)d;
  float gx = __expf(-fmaxf(d * w_gx[f] + b_gx[f], 0.f));
  float xh = gx * L[g] + (1.f - gx) * Mean[(size_t)b * 256 + f];
  float m  = Msk[g];
  float xr = m * X[g] + (1.f - m) * xh;
  if (tl < 16) {
    size_t xo = (size_t)row * 512;
    XRs[xo + fs]       = (bf16)xr;
    XRs[xo + 256 + fs] = (bf16)m;
  }
}

// ---------------------------------------------------------------------------
// wprep
// ---------------------------------------------------------------------------
__global__ void wprep_kernel(const float* __restrict__ w_ih, const float* __restrict__ w_hh,
                             const float* __restrict__ b_ih, const float* __restrict__ b_hh,
                             const float* __restrict__ w_gh,
                             bf16* __restrict__ WcH3, bf16* __restrict__ WcX3,
                             bf16* __restrict__ Wgs, float* __restrict__ bias4) {
  int i = blockIdx.x * 256 + threadIdx.x;
  if (i < 4194304) {                       // WcH3: [nb32][kt16][nl128][c8][e8], nl=g*32+jj
    int blk = i >> 13;
    int nb = blk >> 4, kt = blk & 15;
    int r = i & 8191;
    int nl = r >> 6, cc = (r >> 3) & 7, e = r & 7;
    int gg = nl >> 5, j = nb * 32 + (nl & 31);
    int k = kt * 64 + ((cc ^ (nl & 7)) << 3) + e;
    float v;
    if (gg == 3) v = w_hh[(size_t)(2048 + j) * 1024 + k];
    else {
      int rr = gg * 1024 + j;
      v = w_ih[(size_t)rr * 1536 + 256 + k];
      if (gg < 2) v += w_hh[(size_t)rr * 1024 + k];
    }
    WcH3[i] = (bf16)v;
  } else if (i < 5767168) {                // WcX3: [nb24][kt8][nl128][c8][e8], n=g*1024+j
    int q = i - 4194304;
    int blk = q >> 13;
    int nb = blk >> 3, kt = blk & 7;
    int r = q & 8191;
    int nl = r >> 6, cc = (r >> 3) & 7, e = r & 7;
    int gg = nb >> 3;                       // 0..2
    int j  = (nb & 7) * 128 + nl;
    int rr = gg * 1024 + j;
    int k = kt * 64 + ((cc ^ (nl & 7)) << 3) + e;
    float v = (k < 256) ? w_ih[(size_t)rr * 1536 + k]
                        : w_ih[(size_t)rr * 1536 + 1280 + (k - 256)];
    WcX3[q] = (bf16)v;
  } else if (i < 6029312) {                // Wgs
    int q = i - 5767168;
    int blk = q >> 13;
    int nb = blk >> 2, kt = blk & 3;
    int r = q & 8191;
    int nl = r >> 6, cc = (r >> 3) & 7, e = r & 7;
    int n = nb * 128 + nl;
    int k = kt * 64 + ((cc ^ (nl & 7)) << 3) + e;
    Wgs[q] = (bf16)w_gh[(size_t)n * 256 + k];
  } else if (i < 6033408) {                // bias4
    int q = i - 6029312;
    int gg = q >> 10, j = q & 1023;
    float v;
    if (gg == 0)      v = b_ih[j] + b_hh[j];
    else if (gg == 1) v = b_ih[1024 + j] + b_hh[1024 + j];
    else if (gg == 2) v = b_ih[2048 + j];
    else              v = b_hh[2048 + j];
    bias4[q] = v;
  }
}

// ---------------------------------------------------------------------------
// gammah: single-buffered 32KB (5 blocks/CU, one residency round for 1088 blks)
// grid nsl*64; validated structure from R9's gammah role.
// ---------------------------------------------------------------------------
__global__ __launch_bounds__(256) void gammah_kernel(const bf16* __restrict__ Dbfs,
                                                     const bf16* __restrict__ Wgs,
                                                     const float* __restrict__ b_gh,
                                                     bf16* __restrict__ GH) {
  __shared__ char smem[32768];
  char* As = smem;
  char* Bs = smem + 16384;
  int tid = threadIdx.x, lane = tid & 63, wid = tid >> 6;
  int wr = wid >> 1, wc = wid & 1;
  int slice = blockIdx.x >> 6, sub = blockIdx.x & 63;
  int mb = sub >> 3, nb = sub & 7;

  const bf16* aA = Dbfs + ((size_t)(slice * 1024 + mb * 128 + wid * 8 + (lane >> 3))) * 256 + (lane & 7) * 8;
  const bf16* aB = Wgs + (size_t)nb * 32768 + wid * 512 + lane * 8;

  f32x4 acc[4][4];
#pragma unroll
  for (int a = 0; a < 4; ++a)
#pragma unroll
    for (int b = 0; b < 4; ++b)
#pragma unroll
      for (int q = 0; q < 4; ++q) acc[a][b][q] = 0.f;

  for (int kt = 0; kt < 4; ++kt) {
#pragma unroll
    for (int q = 0; q < 4; ++q)
      GLL16(aA + q * (32 * 256) + kt * 64, As + (q * 4 + wid) * 1024);
#pragma unroll
    for (int q = 0; q < 4; ++q)
      GLL16(aB + kt * 8192 + q * 2048, Bs + (q * 4 + wid) * 1024);
    __syncthreads();
#pragma unroll
    for (int kk = 0; kk < 2; ++kk) {
      int kb = kk * 64 + ((lane >> 4) << 4);
      bf16x8 af[4], bfr[4];
#pragma unroll
      for (int mf = 0; mf < 4; ++mf) {
        int row = wr * 64 + mf * 16 + (lane & 15);
        af[mf] = *(const bf16x8*)(As + (((row * 128 + kb)) ^ ((row & 7) << 4)));
      }
#pragma unroll
      for (int nf = 0; nf < 4; ++nf) {
        int nl = wc * 64 + nf * 16 + (lane & 15);
        bfr[nf] = *(const bf16x8*)(Bs + (((nl * 128 + kb)) ^ ((nl & 7) << 4)));
      }
#pragma unroll
      for (int mf = 0; mf < 4; ++mf)
#pragma unroll
        for (int nf = 0; nf < 4; ++nf)
          acc[mf][nf] = __builtin_amdgcn_mfma_f32_16x16x32_bf16(af[mf], bfr[nf], acc[mf][nf], 0, 0, 0);
    }
    __syncthreads();
  }
  char* ep = smem;   // 128 rows x 256B = 32KB
#pragma unroll
  for (int nf = 0; nf < 4; ++nf) {
    int col = wc * 64 + nf * 16 + (lane & 15);
    float bg = b_gh[nb * 128 + col];
#pragma unroll
    for (int mf = 0; mf < 4; ++mf)
#pragma unroll
      for (int reg = 0; reg < 4; ++reg) {
        int row = wr * 64 + mf * 16 + ((lane >> 4) << 2) + reg;
        int cph = ((col >> 3) ^ (((row >> 2) & 3) << 2));
        *(bf16*)(ep + row * 256 + (cph << 4) + (col & 7) * 2) =
            (bf16)__expf(-fmaxf(acc[mf][nf][reg] + bg, 0.f));
      }
  }
  __syncthreads();
#pragma unroll
  for (int p = 0; p < 8; ++p) {
    int idx = p * 256 + tid;
    int row = idx >> 4, c = idx & 15;
    int cph = c ^ (((row >> 2) & 3) << 2);
    bf16x8 v = *(const bf16x8*)(ep + row * 256 + (cph << 4));
    *(bf16x8*)(GH + (size_t)(slice * 1024 + mb * 128 + row) * 1024 + nb * 128 + c * 8) = v;
  }
}

// ---------------------------------------------------------------------------
// gix: Gi[slice][g][b][j] = XRs . WcX^T (3 gate planes); R7 unchanged
// ---------------------------------------------------------------------------
__global__ __launch_bounds__(256) void gix_kernel(const bf16* __restrict__ XRs,
                                                  const bf16* __restrict__ WcX3,
                                                  bf16* __restrict__ Gi) {
  __shared__ char smem[65536];
  char* As = smem;
  char* Bs = smem + 32768;
  int tid = threadIdx.x, lane = tid & 63, wid = tid >> 6;
  int wr = wid >> 1, wc = wid & 1;
  int cpx = gridDim.x >> 3;
  int wg = (blockIdx.x & 7) * cpx + (blockIdx.x >> 3);
  int nb = wg % 24, mb = wg / 24;

  const bf16* aA = XRs + ((size_t)(mb * 128 + wid * 8 + (lane >> 3))) * 512 + (lane & 7) * 8;
  const bf16* aB = WcX3 + (size_t)nb * 8 * 8192 + wid * 512 + lane * 8;

  f32x4 acc[4][4];
#pragma unroll
  for (int a = 0; a < 4; ++a)
#pragma unroll
    for (int b = 0; b < 4; ++b)
#pragma unroll
      for (int q = 0; q < 4; ++q) acc[a][b][q] = 0.f;

#define GX_STAGE(buf, kt)                                                         \
  do {                                                                            \
    _Pragma("unroll")                                                             \
    for (int q = 0; q < 4; ++q)                                                   \
      GLL16(aA + q * (32 * 512) + (kt) * 64, As + (buf) * 16384 + (q * 4 + wid) * 1024); \
    _Pragma("unroll")                                                             \
    for (int q = 0; q < 4; ++q)                                                   \
      GLL16(aB + (size_t)(kt) * 8192 + q * 2048, Bs + (buf) * 16384 + (q * 4 + wid) * 1024); \
  } while (0)

  GX_STAGE(0, 0);
  __syncthreads();
  for (int kt = 0; kt < 8; ++kt) {
    const int cur = kt & 1;
    if (kt < 7) GX_STAGE(cur ^ 1, kt + 1);
#pragma unroll
    for (int kk = 0; kk < 2; ++kk) {
      int kb = kk * 64 + ((lane >> 4) << 4);
      bf16x8 af[4], bfr[4];
#pragma unroll
      for (int mf = 0; mf < 4; ++mf) {
        int row = wr * 64 + mf * 16 + (lane & 15);
        af[mf] = *(const bf16x8*)(As + cur * 16384 + (((row * 128 + kb)) ^ ((row & 7) << 4)));
      }
#pragma unroll
      for (int nf = 0; nf < 4; ++nf) {
        int nl = wc * 64 + nf * 16 + (lane & 15);
        bfr[nf] = *(const bf16x8*)(Bs + cur * 16384 + (((nl * 128 + kb)) ^ ((nl & 7) << 4)));
      }
#pragma unroll
      for (int mf = 0; mf < 4; ++mf)
#pragma unroll
        for (int nf = 0; nf < 4; ++nf)
          acc[mf][nf] = __builtin_amdgcn_mfma_f32_16x16x32_bf16(af[mf], bfr[nf], acc[mf][nf], 0, 0, 0);
    }
    __syncthreads();
  }
  char* ep = smem;
#pragma unroll
  for (int nf = 0; nf < 4; ++nf) {
    int col = wc * 64 + nf * 16 + (lane & 15);
#pragma unroll
    for (int mf = 0; mf < 4; ++mf)
#pragma unroll
      for (int reg = 0; reg < 4; ++reg) {
        int row = wr * 64 + mf * 16 + ((lane >> 4) << 2) + reg;
        int cph = ((col >> 3) ^ (((row >> 2) & 3) << 2));
        *(bf16*)(ep + row * 256 + (cph << 4) + (col & 7) * 2) = (bf16)acc[mf][nf][reg];
      }
  }
  __syncthreads();
  {
    int sl = mb >> 3, mbl = mb & 7;
    bf16* plane = Gi + (size_t)sl * 3145728 + (size_t)(nb >> 3) * 1048576 + (nb & 7) * 128;
#pragma unroll
    for (int p = 0; p < 8; ++p) {
      int idx = p * 256 + tid;
      int row = idx >> 4, c = idx & 15;
      int cph = c ^ (((row >> 2) & 3) << 2);
      bf16x8 v = *(const bf16x8*)(ep + row * 256 + (cph << 4));
      *(bf16x8*)(plane + (size_t)(mbl * 128 + row) * 1024 + c * 8) = v;
    }
  }
}

// ---------------------------------------------------------------------------
// step: 64x128 tile, 512 threads, 2x4 wave grid (A-dup x4, B-dup x2:
// 64KB LDS reads/iter vs 80KB in 4x2). B-frag pairs gates {0,1}/{2,3};
// epilogue recovers all-4-gates-per-lane with 4 shfl_xor(8).
// Counted-vmcnt pipeline (R10 structure).
// ---------------------------------------------------------------------------
__global__ __launch_bounds__(512) void step_kernel(
    const bf16* __restrict__ hbs, const float* __restrict__ hf,
    const bf16* __restrict__ WcH3, const float* __restrict__ bias4,
    const bf16* __restrict__ gi, const bf16* __restrict__ gh_next, int is_last,
    float* __restrict__ hf_next, bf16* __restrict__ hbs_next) {
  __shared__ char smem[49152];   // A [2][8192] @0, B [2][16384] @16384
  int tid = threadIdx.x, lane = tid & 63, wid = tid >> 6;
  int wr = wid >> 2, wc = wid & 3;          // 2x4 wave grid
  int wg = ((blockIdx.x & 7) << 6) + (blockIdx.x >> 3);
  int mb = wg & 15, nb = wg >> 4;

  const bf16* aA = hbs + ((size_t)(mb * 64 + (tid >> 3))) * 1024 + (tid & 7) * 8;
  const bf16* aB = WcH3 + (size_t)nb * 131072 + tid * 8;

  // post-shuffle ownership: lane bit3 selects m-fragment; j = wc*8 + lane&7
  int mSel = (lane >> 3) & 1;
  int j = nb * 32 + wc * 8 + (lane & 7);

  // ---- epilogue prefetch (oldest in vmcnt order) ----
  bf16  grv[4], gzv[4], gnv[4], ghv[4];
  float hfv[4];
#pragma unroll
  for (int reg = 0; reg < 4; ++reg) {
    int brow = mb * 64 + wr * 32 + mSel * 16 + ((lane >> 4) << 2) + reg;
    size_t hb_ = (size_t)brow * 1024 + j;
    grv[reg] = gi[hb_];
    gzv[reg] = gi[1048576 + hb_];
    gnv[reg] = gi[2097152 + hb_];
    ghv[reg] = gh_next[hb_];
    hfv[reg] = hf[hb_];
  }

  f32x4 acc[2][2];   // [m-frag][gate-pair frag]
#pragma unroll
  for (int a = 0; a < 2; ++a)
#pragma unroll
    for (int b = 0; b < 2; ++b)
#pragma unroll
      for (int q = 0; q < 4; ++q) acc[a][b][q] = 0.f;

#define ST_STAGE(buf, kt)                                                         \
  do {                                                                            \
    GLL16(aA + (kt) * 64,                 smem + (buf) * 8192 + wid * 1024);      \
    GLL16(aB + (kt) * 8192,               smem + 16384 + (buf) * 16384 + wid * 1024); \
    GLL16(aB + (kt) * 8192 + 4096,        smem + 16384 + (buf) * 16384 + 8192 + wid * 1024); \
  } while (0)

  ST_STAGE(0, 0);
  for (int kt = 0; kt < 16; ++kt) {
    const int cur = kt & 1;
    if (kt < 15) {
      ST_STAGE(cur ^ 1, kt + 1);
      asm volatile("s_waitcnt vmcnt(3)" ::: "memory");
    } else {
      asm volatile("s_waitcnt vmcnt(0)" ::: "memory");
    }
    __builtin_amdgcn_sched_barrier(0);
    __builtin_amdgcn_s_barrier();
    __builtin_amdgcn_sched_barrier(0);
    const char* Ab = smem + cur * 8192;
    const char* Bb = smem + 16384 + cur * 16384;
#pragma unroll
    for (int kk = 0; kk < 2; ++kk) {
      int kb = kk * 64 + ((lane >> 4) << 4);
      bf16x8 af[2], bfr[2];
#pragma unroll
      for (int m = 0; m < 2; ++m) {
        int row = wr * 32 + m * 16 + (lane & 15);
        af[m] = *(const bf16x8*)(Ab + (((row * 128 + kb)) ^ ((row & 7) << 4)));
      }
#pragma unroll
      for (int f = 0; f < 2; ++f) {
        int nl = (f * 2 + ((lane & 15) >> 3)) * 32 + wc * 8 + (lane & 7);
        bfr[f] = *(const bf16x8*)(Bb + (((nl * 128 + kb)) ^ ((nl & 7) << 4)));
      }
#pragma unroll
      for (int m = 0; m < 2; ++m)
#pragma unroll
        for (int f = 0; f < 2; ++f)
          acc[m][f] = __builtin_amdgcn_mfma_f32_16x16x32_bf16(af[m], bfr[f], acc[m][f], 0, 0, 0);
    }
    asm volatile("s_waitcnt lgkmcnt(0)" ::: "memory");
    __builtin_amdgcn_sched_barrier(0);
    __builtin_amdgcn_s_barrier();
  }

  // ---- gate exchange: lane L (bit3=0) holds g{0,2}, lane L+8 holds g{1,3}
  // of the same j. 4 shfl_xor(8) give each lane all 4 gates of its mSel frag.
  float sh00[4], sh01[4], sh10[4], sh11[4];
#pragma unroll
  for (int q = 0; q < 4; ++q) {
    sh00[q] = __shfl_xor(acc[0][0][q], 8);
    sh01[q] = __shfl_xor(acc[0][1][q], 8);
    sh10[q] = __shfl_xor(acc[1][0][q], 8);
    sh11[q] = __shfl_xor(acc[1][1][q], 8);
  }
  int hi = mSel;   // bit3 of lane
  float br = bias4[j], bz = bias4[1024 + j], bn = bias4[2048 + j], bh = bias4[3072 + j];
#pragma unroll
  for (int reg = 0; reg < 4; ++reg) {
    float g0 = hi ? sh10[reg]      : acc[0][0][reg];
    float g1 = hi ? acc[1][0][reg] : sh00[reg];
    float g2 = hi ? sh11[reg]      : acc[0][1][reg];
    float g3 = hi ? acc[1][1][reg] : sh01[reg];
    int brow = mb * 64 + wr * 32 + mSel * 16 + ((lane >> 4) << 2) + reg;
    float pr  = g0 + (float)grv[reg] + br;
    float pz  = g1 + (float)gzv[reg] + bz;
    float pin = g2 + (float)gnv[reg] + bn;
    float phn = g3 + bh;
    float r = sigm(pr), z = sigm(pz);
    float nn = tanh_fast(pin + r * phn);
    float hnew = (1.f - z) * nn + z * hfv[reg];
    float gam = is_last ? 1.f : (float)ghv[reg];
    float hd = hnew * gam;
    hf_next[(size_t)brow * 1024 + j] = hd;
    hbs_next[(size_t)brow * 1024 + (j ^ ((brow & 7) << 3))] = (bf16)hd;
  }
}

// ---------------------------------------------------------------------------
// classifier + softmax
// ---------------------------------------------------------------------------
__global__ void cls_kernel(const float* __restrict__ h, const float* __restrict__ w_cls,
                           const float* __restrict__ b_cls, float* __restrict__ out) {
  int wid = threadIdx.x >> 6, lane = threadIdx.x & 63;
  int b = blockIdx.x * 4 + wid;
  const float* hb = h + (size_t)b * 1024;
  float a0 = 0.f, a1 = 0.f;
#pragma unroll
  for (int e = 0; e < 16; ++e) {
    int i = e * 64 + lane;
    float hv = hb[i];
    a0 += hv * w_cls[i];
    a1 += hv * w_cls[1024 + i];
  }
  for (int off = 32; off; off >>= 1) {
    a0 += __shfl_down(a0, off);
    a1 += __shfl_down(a1, off);
  }
  if (lane == 0) {
    float l0 = a0 + b_cls[0], l1 = a1 + b_cls[1];
    float mx = fmaxf(l0, l1);
    float e0 = __expf(l0 - mx), e1 = __expf(l1 - mx);
    float s = e0 + e1;
    out[b * 2]     = e0 / s;
    out[b * 2 + 1] = e1 / s;
  }
}

// ---------------------------------------------------------------------------
extern "C" void kernel_launch(void* const* d_in, const int* in_sizes, int n_in,
                              void* d_out, int out_size, void* d_ws, size_t ws_size,
                              hipStream_t stream) {
  const float* X     = (const float*)d_in[0];
  const float* Msk   = (const float*)d_in[1];
  const float* D     = (const float*)d_in[2];
  const float* Mean  = (const float*)d_in[3];
  const float* L     = (const float*)d_in[4];
  const float* w_gh  = (const float*)d_in[5];
  const float* b_gh  = (const float*)d_in[6];
  const float* w_gx  = (const float*)d_in[7];
  const float* b_gx  = (const float*)d_in[8];
  const float* w_ih  = (const float*)d_in[9];
  const float* w_hh  = (const float*)d_in[10];
  const float* b_ih  = (const float*)d_in[11];
  const float* b_hh  = (const float*)d_in[12];
  const float* w_cls = (const float*)d_in[13];
  const float* b_cls = (const float*)d_in[14];

  char* w = (char*)d_ws;
  bf16*  XRs   = (bf16*)(w);
  bf16*  Dbfs  = (bf16*)(w + 16777216);
  bf16*  GH    = (bf16*)(w + 25690112);
  bf16*  WcX3  = (bf16*)(w + 61341696);
  bf16*  WcH3  = (bf16*)(w + 65536000);
  bf16*  Wgs   = (bf16*)(w + 73924608);
  float* bias4 = (float*)(w + 74448896);
  float* hf0   = (float*)(w + 74465280);
  float* hf1   = (float*)(w + 78659584);
  bf16*  hb0   = (bf16*)(w + 82853888);
  bf16*  hb1   = (bf16*)(w + 84951040);
  bf16*  Gi    = (bf16*)(w + 87048192);

  size_t base = 87048192;
  int GCH = 16;
  while (GCH > 1 && base + (size_t)GCH * 6291456ull > ws_size) GCH >>= 1;

  float* hfp[2] = {hf0, hf1};
  bf16*  hbp[2] = {hb0, hb1};

  hipMemsetAsync(hf0, 0, 4194304, stream);
  hipMemsetAsync(hb0, 0, 2097152, stream);
  wprep_kernel<<<23568, 256, 0, stream>>>(w_ih, w_hh, b_ih, b_hh, w_gh, WcH3, WcX3, Wgs, bias4);

  int t = 0;
  for (int c = 0; c < 4; ++c) {
    int nsl = (c < 3) ? 17 : 16;
    prep_kernel<<<nsl * 1024, 256, 0, stream>>>(X, Msk, D, Mean, L, w_gx, b_gx, XRs, Dbfs, c, nsl);
    gammah_kernel<<<nsl * 64, 256, 0, stream>>>(Dbfs, Wgs, b_gh, GH);
    for (int sub = 0; sub < 16 / GCH; ++sub) {
      gix_kernel<<<GCH * 192, 256, 0, stream>>>(XRs + (size_t)sub * GCH * 524288, WcX3, Gi);
      for (int tl2 = 0; tl2 < GCH; ++tl2, ++t) {
        int tl = sub * GCH + tl2;
        int cur = t & 1, nxt = cur ^ 1;
        step_kernel<<<512, 512, 0, stream>>>(
            hbp[cur], hfp[cur], WcH3, bias4,
            Gi + (size_t)tl2 * 3145728, GH + (size_t)(tl + 1) * 1048576,
            (t == 63) ? 1 : 0, hfp[nxt], hbp[nxt]);
      }
    }
  }
  cls_kernel<<<256, 256, 0, stream>>>(hfp[0], w_cls, b_cls, (float*)d_out);
}

// Round 13
// 1292.237 us; speedup vs baseline: 1.1069x; 1.1069x over previous
//
#include <hip/hip_runtime.h>

using bf16   = __bf16;
using bf16x8 = __bf16 __attribute__((ext_vector_type(8)));
using f32x4  = float  __attribute__((ext_vector_type(4)));
using i32x4  = int    __attribute__((ext_vector_type(4)));

// B=1024, T=64, F=256, H=1024, C=2
// ws layout: identical to R7/R10. WcH3 region holds i8 weights (4MB of 8MB).
// hb0/hb1 (2MB each) hold TWO i8 planes: hi (x128) @0, lo (x16384 residual) @1MB.
// Weight scales: gates 0,1 (r,z: w_ih+w_hh, |w|<=1/16) x2048;
//                gates 2,3 (n paths, single matrix, |w|<=1/32) x4096.
// preact_g = acc_hi/(128*Sw_g) + acc_lo/(16384*Sw_g).

__device__ __forceinline__ float sigm(float x) { return 1.f / (1.f + __expf(-x)); }
__device__ __forceinline__ float tanh_fast(float x) {
  float e = __expf(2.f * x);
  return 1.f - 2.f / (e + 1.f);
}

#define GLL16(gsrc, ldst)                                                              \
  __builtin_amdgcn_global_load_lds((const __attribute__((address_space(1))) void*)(gsrc), \
                                   (__attribute__((address_space(3))) void*)(ldst), 16, 0, 0)

// ---------------------------------------------------------------------------
// prep: pre-swizzled XRs ([xr|m], f XOR (b&7)<<3) and Dbfs   (unchanged)
// ---------------------------------------------------------------------------
__global__ void prep_kernel(const float* __restrict__ X, const float* __restrict__ Msk,
                            const float* __restrict__ D, const float* __restrict__ Mean,
                            const float* __restrict__ L, const float* __restrict__ w_gx,
                            const float* __restrict__ b_gx,
                            bf16* __restrict__ XRs, bf16* __restrict__ Dbfs,
                            int c, int nsl) {
  int i = blockIdx.x * 256 + threadIdx.x;
  if (i >= (nsl << 18)) return;
  int f = i & 255, b = (i >> 8) & 1023, tl = i >> 18;
  int t = c * 16 + tl;
  size_t g = ((size_t)b << 14) + ((size_t)t << 8) + f;
  float d = D[g];
  int fs = f ^ ((b & 7) << 3);
  int row = tl * 1024 + b;
  Dbfs[(size_t)row * 256 + fs] = (bf16)d;
  float gx = __expf(-fmaxf(d * w_gx[f] + b_gx[f], 0.f));
  float xh = gx * L[g] + (1.f - gx) * Mean[(size_t)b * 256 + f];
  float m  = Msk[g];
  float xr = m * X[g] + (1.f - m) * xh;
  if (tl < 16) {
    size_t xo = (size_t)row * 512;
    XRs[xo + fs]       = (bf16)xr;
    XRs[xo + 256 + fs] = (bf16)m;
  }
}

// ---------------------------------------------------------------------------
// wprep: WcH3 i8 [nb32][kt8][nl128][128B] with per-gate scales
// ---------------------------------------------------------------------------
__global__ void wprep_kernel(const float* __restrict__ w_ih, const float* __restrict__ w_hh,
                             const float* __restrict__ b_ih, const float* __restrict__ b_hh,
                             const float* __restrict__ w_gh,
                             char* __restrict__ WcH3, bf16* __restrict__ WcX3,
                             bf16* __restrict__ Wgs, float* __restrict__ bias4) {
  int i = blockIdx.x * 256 + threadIdx.x;
  if (i < 4194304) {                       // WcH3 i8: [nb32][kt8][nl128][cc8][e16]
    int nb = i >> 17;
    int rem = i & 131071;
    int kt = rem >> 14;
    int r2 = rem & 16383;
    int nl = r2 >> 7, bb = r2 & 127;
    int cc = bb >> 4, e = bb & 15;
    int gg = nl >> 5, j = nb * 32 + (nl & 31);
    int k = kt * 128 + ((cc ^ (nl & 7)) << 4) + e;
    float v;
    if (gg == 3) v = w_hh[(size_t)(2048 + j) * 1024 + k];
    else {
      int rr = gg * 1024 + j;
      v = w_ih[(size_t)rr * 1536 + 256 + k];
      if (gg < 2) v += w_hh[(size_t)rr * 1024 + k];
    }
    float sc = (gg >= 2) ? 4096.f : 2048.f;
    int wq = __float2int_rn(v * sc);
    wq = wq > 127 ? 127 : (wq < -127 ? -127 : wq);
    WcH3[i] = (char)wq;
  } else if (i < 5767168) {                // WcX3: [nb24][kt8][nl128][c8][e8], n=g*1024+j
    int q = i - 4194304;
    int blk = q >> 13;
    int nb = blk >> 3, kt = blk & 7;
    int r = q & 8191;
    int nl = r >> 6, cc = (r >> 3) & 7, e = r & 7;
    int gg = nb >> 3;                       // 0..2
    int j  = (nb & 7) * 128 + nl;
    int rr = gg * 1024 + j;
    int k = kt * 64 + ((cc ^ (nl & 7)) << 3) + e;
    float v = (k < 256) ? w_ih[(size_t)rr * 1536 + k]
                        : w_ih[(size_t)rr * 1536 + 1280 + (k - 256)];
    WcX3[q] = (bf16)v;
  } else if (i < 6029312) {                // Wgs
    int q = i - 5767168;
    int blk = q >> 13;
    int nb = blk >> 2, kt = blk & 3;
    int r = q & 8191;
    int nl = r >> 6, cc = (r >> 3) & 7, e = r & 7;
    int n = nb * 128 + nl;
    int k = kt * 64 + ((cc ^ (nl & 7)) << 3) + e;
    Wgs[q] = (bf16)w_gh[(size_t)n * 256 + k];
  } else if (i < 6033408) {                // bias4
    int q = i - 6029312;
    int gg = q >> 10, j = q & 1023;
    float v;
    if (gg == 0)      v = b_ih[j] + b_hh[j];
    else if (gg == 1) v = b_ih[1024 + j] + b_hh[1024 + j];
    else if (gg == 2) v = b_ih[2048 + j];
    else              v = b_hh[2048 + j];
    bias4[q] = v;
  }
}

// ---------------------------------------------------------------------------
// gammah: R10 double-buffered version (unchanged)
// ---------------------------------------------------------------------------
__global__ __launch_bounds__(256) void gammah_kernel(const bf16* __restrict__ Dbfs,
                                                     const bf16* __restrict__ Wgs,
                                                     const float* __restrict__ b_gh,
                                                     bf16* __restrict__ GH) {
  __shared__ char smem[65536];
  char* As = smem;
  char* Bs = smem + 32768;
  int tid = threadIdx.x, lane = tid & 63, wid = tid >> 6;
  int wr = wid >> 1, wc = wid & 1;
  int cpx = gridDim.x >> 3;
  int wg = (blockIdx.x & 7) * cpx + (blockIdx.x >> 3);
  int nb = wg & 7, mb = wg >> 3;

  const bf16* aA = Dbfs + ((size_t)(mb * 128 + wid * 8 + (lane >> 3))) * 256 + (lane & 7) * 8;
  const bf16* aB = Wgs + (size_t)nb * 4 * 8192 + wid * 512 + lane * 8;

  f32x4 acc[4][4];
#pragma unroll
  for (int a = 0; a < 4; ++a)
#pragma unroll
    for (int b = 0; b < 4; ++b)
#pragma unroll
      for (int q = 0; q < 4; ++q) acc[a][b][q] = 0.f;

#define GM_STAGE(buf, kt)                                                         \
  do {                                                                            \
    _Pragma("unroll")                                                             \
    for (int q = 0; q < 4; ++q)                                                   \
      GLL16(aA + q * (32 * 256) + (kt) * 64, As + (buf) * 16384 + (q * 4 + wid) * 1024); \
    _Pragma("unroll")                                                             \
    for (int q = 0; q < 4; ++q)                                                   \
      GLL16(aB + (size_t)(kt) * 8192 + q * 2048, Bs + (buf) * 16384 + (q * 4 + wid) * 1024); \
  } while (0)

  GM_STAGE(0, 0);
  __syncthreads();
  for (int kt = 0; kt < 4; ++kt) {
    const int cur = kt & 1;
    if (kt < 3) GM_STAGE(cur ^ 1, kt + 1);
#pragma unroll
    for (int kk = 0; kk < 2; ++kk) {
      int kb = kk * 64 + ((lane >> 4) << 4);
      bf16x8 af[4], bfr[4];
#pragma unroll
      for (int mf = 0; mf < 4; ++mf) {
        int row = wr * 64 + mf * 16 + (lane & 15);
        af[mf] = *(const bf16x8*)(As + cur * 16384 + (((row * 128 + kb)) ^ ((row & 7) << 4)));
      }
#pragma unroll
      for (int nf = 0; nf < 4; ++nf) {
        int nl = wc * 64 + nf * 16 + (lane & 15);
        bfr[nf] = *(const bf16x8*)(Bs + cur * 16384 + (((nl * 128 + kb)) ^ ((nl & 7) << 4)));
      }
#pragma unroll
      for (int mf = 0; mf < 4; ++mf)
#pragma unroll
        for (int nf = 0; nf < 4; ++nf)
          acc[mf][nf] = __builtin_amdgcn_mfma_f32_16x16x32_bf16(af[mf], bfr[nf], acc[mf][nf], 0, 0, 0);
    }
    __syncthreads();
  }
  char* ep = smem;
#pragma unroll
  for (int nf = 0; nf < 4; ++nf) {
    int col = wc * 64 + nf * 16 + (lane & 15);
    float bg = b_gh[nb * 128 + col];
#pragma unroll
    for (int mf = 0; mf < 4; ++mf)
#pragma unroll
      for (int reg = 0; reg < 4; ++reg) {
        int row = wr * 64 + mf * 16 + ((lane >> 4) << 2) + reg;
        int cph = ((col >> 3) ^ (((row >> 2) & 3) << 2));
        *(bf16*)(ep + row * 256 + (cph << 4) + (col & 7) * 2) =
            (bf16)__expf(-fmaxf(acc[mf][nf][reg] + bg, 0.f));
      }
  }
  __syncthreads();
#pragma unroll
  for (int p = 0; p < 8; ++p) {
    int idx = p * 256 + tid;
    int row = idx >> 4, c = idx & 15;
    int cph = c ^ (((row >> 2) & 3) << 2);
    bf16x8 v = *(const bf16x8*)(ep + row * 256 + (cph << 4));
    *(bf16x8*)(GH + (size_t)(mb * 128 + row) * 1024 + nb * 128 + c * 8) = v;
  }
}

// ---------------------------------------------------------------------------
// gix: unchanged from R10
// ---------------------------------------------------------------------------
__global__ __launch_bounds__(256) void gix_kernel(const bf16* __restrict__ XRs,
                                                  const bf16* __restrict__ WcX3,
                                                  bf16* __restrict__ Gi) {
  __shared__ char smem[65536];
  char* As = smem;
  char* Bs = smem + 32768;
  int tid = threadIdx.x, lane = tid & 63, wid = tid >> 6;
  int wr = wid >> 1, wc = wid & 1;
  int cpx = gridDim.x >> 3;
  int wg = (blockIdx.x & 7) * cpx + (blockIdx.x >> 3);
  int nb = wg % 24, mb = wg / 24;

  const bf16* aA = XRs + ((size_t)(mb * 128 + wid * 8 + (lane >> 3))) * 512 + (lane & 7) * 8;
  const bf16* aB = WcX3 + (size_t)nb * 8 * 8192 + wid * 512 + lane * 8;

  f32x4 acc[4][4];
#pragma unroll
  for (int a = 0; a < 4; ++a)
#pragma unroll
    for (int b = 0; b < 4; ++b)
#pragma unroll
      for (int q = 0; q < 4; ++q) acc[a][b][q] = 0.f;

#define GX_STAGE(buf, kt)                                                         \
  do {                                                                            \
    _Pragma("unroll")                                                             \
    for (int q = 0; q < 4; ++q)                                                   \
      GLL16(aA + q * (32 * 512) + (kt) * 64, As + (buf) * 16384 + (q * 4 + wid) * 1024); \
    _Pragma("unroll")                                                             \
    for (int q = 0; q < 4; ++q)                                                   \
      GLL16(aB + (size_t)(kt) * 8192 + q * 2048, Bs + (buf) * 16384 + (q * 4 + wid) * 1024); \
  } while (0)

  GX_STAGE(0, 0);
  __syncthreads();
  for (int kt = 0; kt < 8; ++kt) {
    const int cur = kt & 1;
    if (kt < 7) GX_STAGE(cur ^ 1, kt + 1);
#pragma unroll
    for (int kk = 0; kk < 2; ++kk) {
      int kb = kk * 64 + ((lane >> 4) << 4);
      bf16x8 af[4], bfr[4];
#pragma unroll
      for (int mf = 0; mf < 4; ++mf) {
        int row = wr * 64 + mf * 16 + (lane & 15);
        af[mf] = *(const bf16x8*)(As + cur * 16384 + (((row * 128 + kb)) ^ ((row & 7) << 4)));
      }
#pragma unroll
      for (int nf = 0; nf < 4; ++nf) {
        int nl = wc * 64 + nf * 16 + (lane & 15);
        bfr[nf] = *(const bf16x8*)(Bs + cur * 16384 + (((nl * 128 + kb)) ^ ((nl & 7) << 4)));
      }
#pragma unroll
      for (int mf = 0; mf < 4; ++mf)
#pragma unroll
        for (int nf = 0; nf < 4; ++nf)
          acc[mf][nf] = __builtin_amdgcn_mfma_f32_16x16x32_bf16(af[mf], bfr[nf], acc[mf][nf], 0, 0, 0);
    }
    __syncthreads();
  }
  char* ep = smem;
#pragma unroll
  for (int nf = 0; nf < 4; ++nf) {
    int col = wc * 64 + nf * 16 + (lane & 15);
#pragma unroll
    for (int mf = 0; mf < 4; ++mf)
#pragma unroll
      for (int reg = 0; reg < 4; ++reg) {
        int row = wr * 64 + mf * 16 + ((lane >> 4) << 2) + reg;
        int cph = ((col >> 3) ^ (((row >> 2) & 3) << 2));
        *(bf16*)(ep + row * 256 + (cph << 4) + (col & 7) * 2) = (bf16)acc[mf][nf][reg];
      }
  }
  __syncthreads();
  {
    int sl = mb >> 3, mbl = mb & 7;
    bf16* plane = Gi + (size_t)sl * 3145728 + (size_t)(nb >> 3) * 1048576 + (nb & 7) * 128;
#pragma unroll
    for (int p = 0; p < 8; ++p) {
      int idx = p * 256 + tid;
      int row = idx >> 4, c = idx & 15;
      int cph = c ^ (((row >> 2) & 3) << 2);
      bf16x8 v = *(const bf16x8*)(ep + row * 256 + (cph << 4));
      *(bf16x8*)(plane + (size_t)(mbl * 128 + row) * 1024 + c * 8) = v;
    }
  }
}

// ---------------------------------------------------------------------------
// step: dual-plane i8 h-GEMM. 64x128 tile, 512 threads, 4x2 waves, grid 512.
// K=1024 in 8 iters of 128 bytes; mfma_i32_16x16x64_i8, two A planes (hi/lo)
// against shared B tile. LDS 64KB (A_hi 16K, A_lo 16K, B 32K), 2-phase dbuf.
// ---------------------------------------------------------------------------
__global__ __launch_bounds__(512, 4) void step_kernel(
    const char* __restrict__ hbs, const float* __restrict__ hf,
    const char* __restrict__ WcH3, const float* __restrict__ bias4,
    const bf16* __restrict__ gi, const bf16* __restrict__ gh_next, int is_last,
    float* __restrict__ hf_next, char* __restrict__ hbs_next) {
  __shared__ char smem[65536];   // A_hi [2][8192] @0, A_lo [2][8192] @16384, B [2][16384] @32768
  int tid = threadIdx.x, lane = tid & 63, wid = tid >> 6;
  int wr = wid >> 1, wc = wid & 1;
  int wg = ((blockIdx.x & 7) << 6) + (blockIdx.x >> 3);
  int mb = wg & 15, nb = wg >> 4;

  const char* aA = hbs + (size_t)(mb * 64 + (tid >> 3)) * 1024 + (tid & 7) * 16;
  const char* aB = WcH3 + (size_t)nb * 131072 + (tid >> 3) * 128 + (tid & 7) * 16;

  // ---- epilogue prefetch (hidden under the GEMM) ----
  int j = nb * 32 + wc * 16 + (lane & 15);
  bf16  grv[4], gzv[4], gnv[4], ghv[4];
  float hfv[4];
#pragma unroll
  for (int reg = 0; reg < 4; ++reg) {
    int brow = mb * 64 + wr * 16 + ((lane >> 4) << 2) + reg;
    size_t hb_ = (size_t)brow * 1024 + j;
    grv[reg] = gi[hb_];
    gzv[reg] = gi[1048576 + hb_];
    gnv[reg] = gi[2097152 + hb_];
    ghv[reg] = gh_next[hb_];
    hfv[reg] = hf[hb_];
  }

  i32x4 acch[4], accl[4];
#pragma unroll
  for (int b = 0; b < 4; ++b)
#pragma unroll
    for (int q = 0; q < 4; ++q) { acch[b][q] = 0; accl[b][q] = 0; }

#define ST_STAGE(buf, kt)                                                            \
  do {                                                                               \
    GLL16(aA + (kt) * 128,            smem + (buf) * 8192 + wid * 1024);             \
    GLL16(aA + 1048576 + (kt) * 128,  smem + 16384 + (buf) * 8192 + wid * 1024);     \
    GLL16(aB + (kt) * 16384,          smem + 32768 + (buf) * 16384 + wid * 1024);    \
    GLL16(aB + (kt) * 16384 + 8192,   smem + 32768 + (buf) * 16384 + 8192 + wid * 1024); \
  } while (0)

  ST_STAGE(0, 0);
  __syncthreads();
  for (int kt = 0; kt < 8; ++kt) {
    const int cur = kt & 1;
    if (kt < 7) ST_STAGE(cur ^ 1, kt + 1);
    const char* Ah = smem + cur * 8192;
    const char* Al = smem + 16384 + cur * 8192;
    const char* Bb = smem + 32768 + cur * 16384;
#pragma unroll
    for (int kk = 0; kk < 2; ++kk) {
      int kb = kk * 64 + ((lane >> 4) << 4);   // byte offset within 128B row
      int row = wr * 16 + (lane & 15);
      int aoff = row * 128 + (kb ^ ((row & 7) << 4));
      i32x4 afh = *(const i32x4*)(Ah + aoff);
      i32x4 afl = *(const i32x4*)(Al + aoff);
      i32x4 bfr[4];
#pragma unroll
      for (int g = 0; g < 4; ++g) {
        int nl = g * 32 + wc * 16 + (lane & 15);
        bfr[g] = *(const i32x4*)(Bb + ((nl * 128 + (kb ^ ((nl & 7) << 4)))));
      }
#pragma unroll
      for (int g = 0; g < 4; ++g) {
        acch[g] = __builtin_amdgcn_mfma_i32_16x16x64_i8(afh, bfr[g], acch[g], 0, 0, 0);
        accl[g] = __builtin_amdgcn_mfma_i32_16x16x64_i8(afl, bfr[g], accl[g], 0, 0, 0);
      }
    }
    __syncthreads();
  }

  // fused GRU epilogue: preact = acc_hi*ISCH + acc_lo*ISCL (+ Gi + bias)
  const float ISCH_RZ = 3.814697265625e-06f;      // 1/(128*2048)
  const float ISCL_RZ = 2.9802322387695312e-08f;  // 1/(16384*2048)
  const float ISCH_N  = 1.9073486328125e-06f;     // 1/(128*4096)
  const float ISCL_N  = 1.4901161193847656e-08f;  // 1/(16384*4096)
  float br = bias4[j], bz = bias4[1024 + j], bn = bias4[2048 + j], bh = bias4[3072 + j];
#pragma unroll
  for (int reg = 0; reg < 4; ++reg) {
    int brow = mb * 64 + wr * 16 + ((lane >> 4) << 2) + reg;
    float pr  = (float)acch[0][reg] * ISCH_RZ + (float)accl[0][reg] * ISCL_RZ + (float)grv[reg] + br;
    float pz  = (float)acch[1][reg] * ISCH_RZ + (float)accl[1][reg] * ISCL_RZ + (float)gzv[reg] + bz;
    float pin = (float)acch[2][reg] * ISCH_N  + (float)accl[2][reg] * ISCL_N  + (float)gnv[reg] + bn;
    float phn = (float)acch[3][reg] * ISCH_N  + (float)accl[3][reg] * ISCL_N  + bh;
    float r = sigm(pr), z = sigm(pz);
    float nn = tanh_fast(pin + r * phn);
    float hnew = (1.f - z) * nn + z * hfv[reg];
    float gam = is_last ? 1.f : (float)ghv[reg];
    float hd = hnew * gam;
    hf_next[(size_t)brow * 1024 + j] = hd;
    int hi8 = __float2int_rn(hd * 128.f);
    hi8 = hi8 > 127 ? 127 : (hi8 < -127 ? -127 : hi8);
    float res = hd - (float)hi8 * 0.0078125f;
    int lo8 = __float2int_rn(res * 16384.f);
    lo8 = lo8 > 127 ? 127 : (lo8 < -127 ? -127 : lo8);
    size_t so = (size_t)brow * 1024 + (j ^ ((brow & 7) << 4));
    hbs_next[so]           = (char)hi8;
    hbs_next[so + 1048576] = (char)lo8;
  }
}

// ---------------------------------------------------------------------------
// classifier + softmax
// ---------------------------------------------------------------------------
__global__ void cls_kernel(const float* __restrict__ h, const float* __restrict__ w_cls,
                           const float* __restrict__ b_cls, float* __restrict__ out) {
  int wid = threadIdx.x >> 6, lane = threadIdx.x & 63;
  int b = blockIdx.x * 4 + wid;
  const float* hb = h + (size_t)b * 1024;
  float a0 = 0.f, a1 = 0.f;
#pragma unroll
  for (int e = 0; e < 16; ++e) {
    int i = e * 64 + lane;
    float hv = hb[i];
    a0 += hv * w_cls[i];
    a1 += hv * w_cls[1024 + i];
  }
  for (int off = 32; off; off >>= 1) {
    a0 += __shfl_down(a0, off);
    a1 += __shfl_down(a1, off);
  }
  if (lane == 0) {
    float l0 = a0 + b_cls[0], l1 = a1 + b_cls[1];
    float mx = fmaxf(l0, l1);
    float e0 = __expf(l0 - mx), e1 = __expf(l1 - mx);
    float s = e0 + e1;
    out[b * 2]     = e0 / s;
    out[b * 2 + 1] = e1 / s;
  }
}

// ---------------------------------------------------------------------------
extern "C" void kernel_launch(void* const* d_in, const int* in_sizes, int n_in,
                              void* d_out, int out_size, void* d_ws, size_t ws_size,
                              hipStream_t stream) {
  const float* X     = (const float*)d_in[0];
  const float* Msk   = (const float*)d_in[1];
  const float* D     = (const float*)d_in[2];
  const float* Mean  = (const float*)d_in[3];
  const float* L     = (const float*)d_in[4];
  const float* w_gh  = (const float*)d_in[5];
  const float* b_gh  = (const float*)d_in[6];
  const float* w_gx  = (const float*)d_in[7];
  const float* b_gx  = (const float*)d_in[8];
  const float* w_ih  = (const float*)d_in[9];
  const float* w_hh  = (const float*)d_in[10];
  const float* b_ih  = (const float*)d_in[11];
  const float* b_hh  = (const float*)d_in[12];
  const float* w_cls = (const float*)d_in[13];
  const float* b_cls = (const float*)d_in[14];

  char* w = (char*)d_ws;
  bf16*  XRs   = (bf16*)(w);
  bf16*  Dbfs  = (bf16*)(w + 16777216);
  bf16*  GH    = (bf16*)(w + 25690112);
  bf16*  WcX3  = (bf16*)(w + 61341696);
  char*  WcH3  = (char*)(w + 65536000);
  bf16*  Wgs   = (bf16*)(w + 73924608);
  float* bias4 = (float*)(w + 74448896);
  float* hf0   = (float*)(w + 74465280);
  float* hf1   = (float*)(w + 78659584);
  char*  hb0   = (char*)(w + 82853888);
  char*  hb1   = (char*)(w + 84951040);
  bf16*  Gi    = (bf16*)(w + 87048192);

  size_t base = 87048192;
  int GCH = 16;
  while (GCH > 1 && base + (size_t)GCH * 6291456ull > ws_size) GCH >>= 1;

  float* hfp[2] = {hf0, hf1};
  char*  hbp[2] = {hb0, hb1};

  hipMemsetAsync(hf0, 0, 4194304, stream);
  hipMemsetAsync(hb0, 0, 2097152, stream);
  wprep_kernel<<<23568, 256, 0, stream>>>(w_ih, w_hh, b_ih, b_hh, w_gh, WcH3, WcX3, Wgs, bias4);

  int t = 0;
  for (int c = 0; c < 4; ++c) {
    int nsl = (c < 3) ? 17 : 16;
    prep_kernel<<<nsl * 1024, 256, 0, stream>>>(X, Msk, D, Mean, L, w_gx, b_gx, XRs, Dbfs, c, nsl);
    gammah_kernel<<<nsl * 64, 256, 0, stream>>>(Dbfs, Wgs, b_gh, GH);
    for (int sub = 0; sub < 16 / GCH; ++sub) {
      gix_kernel<<<GCH * 192, 256, 0, stream>>>(XRs + (size_t)sub * GCH * 524288, WcX3, Gi);
      for (int tl2 = 0; tl2 < GCH; ++tl2, ++t) {
        int tl = sub * GCH + tl2;
        int cur = t & 1, nxt = cur ^ 1;
        step_kernel<<<512, 512, 0, stream>>>(
            hbp[cur], hfp[cur], WcH3, bias4,
            Gi + (size_t)tl2 * 3145728, GH + (size_t)(tl + 1) * 1048576,
            (t == 63) ? 1 : 0, hfp[nxt], hbp[nxt]);
      }
    }
  }
  cls_kernel<<<256, 256, 0, stream>>>(hfp[0], w_cls, b_cls, (float*)d_out);
}

// Round 14
// 1150.335 us; speedup vs baseline: 1.2434x; 1.1234x over previous
//
#include <hip/hip_runtime.h>

using bf16   = __bf16;
using bf16x8 = __bf16 __attribute__((ext_vector_type(8)));
using f32x4  = float  __attribute__((ext_vector_type(4)));
using i32x4  = int    __attribute__((ext_vector_type(4)));

// B=1024, T=64, F=256, H=1024, C=2
// ws layout: identical to R7/R10. WcH3 holds i8 weights (4MB of 8MB region).
// hb0/hb1: single i8 plane hq = rn(h*128) (|h|<1 by construction).
// Weight scales: gates 0,1 (r,z sums, |w|<=1/16) x2048; gates 2,3 x4096.
// preact_g = acc / (128 * Sw_g).

__device__ __forceinline__ float sigm(float x) { return 1.f / (1.f + __expf(-x)); }
__device__ __forceinline__ float tanh_fast(float x) {
  float e = __expf(2.f * x);
  return 1.f - 2.f / (e + 1.f);
}

#define GLL16(gsrc, ldst)                                                              \
  __builtin_amdgcn_global_load_lds((const __attribute__((address_space(1))) void*)(gsrc), \
                                   (__attribute__((address_space(3))) void*)(ldst), 16, 0, 0)

// ---------------------------------------------------------------------------
// prep: pre-swizzled XRs ([xr|m], f XOR (b&7)<<3) and Dbfs   (unchanged)
// ---------------------------------------------------------------------------
__global__ void prep_kernel(const float* __restrict__ X, const float* __restrict__ Msk,
                            const float* __restrict__ D, const float* __restrict__ Mean,
                            const float* __restrict__ L, const float* __restrict__ w_gx,
                            const float* __restrict__ b_gx,
                            bf16* __restrict__ XRs, bf16* __restrict__ Dbfs,
                            int c, int nsl) {
  int i = blockIdx.x * 256 + threadIdx.x;
  if (i >= (nsl << 18)) return;
  int f = i & 255, b = (i >> 8) & 1023, tl = i >> 18;
  int t = c * 16 + tl;
  size_t g = ((size_t)b << 14) + ((size_t)t << 8) + f;
  float d = D[g];
  int fs = f ^ ((b & 7) << 3);
  int row = tl * 1024 + b;
  Dbfs[(size_t)row * 256 + fs] = (bf16)d;
  float gx = __expf(-fmaxf(d * w_gx[f] + b_gx[f], 0.f));
  float xh = gx * L[g] + (1.f - gx) * Mean[(size_t)b * 256 + f];
  float m  = Msk[g];
  float xr = m * X[g] + (1.f - m) * xh;
  if (tl < 16) {
    size_t xo = (size_t)row * 512;
    XRs[xo + fs]       = (bf16)xr;
    XRs[xo + 256 + fs] = (bf16)m;
  }
}

// ---------------------------------------------------------------------------
// wprep: WcH3 i8 [nb32][kt8][nl128][128B] with per-gate scales (unchanged)
// ---------------------------------------------------------------------------
__global__ void wprep_kernel(const float* __restrict__ w_ih, const float* __restrict__ w_hh,
                             const float* __restrict__ b_ih, const float* __restrict__ b_hh,
                             const float* __restrict__ w_gh,
                             char* __restrict__ WcH3, bf16* __restrict__ WcX3,
                             bf16* __restrict__ Wgs, float* __restrict__ bias4) {
  int i = blockIdx.x * 256 + threadIdx.x;
  if (i < 4194304) {                       // WcH3 i8: [nb32][kt8][nl128][cc8][e16]
    int nb = i >> 17;
    int rem = i & 131071;
    int kt = rem >> 14;
    int r2 = rem & 16383;
    int nl = r2 >> 7, bb = r2 & 127;
    int cc = bb >> 4, e = bb & 15;
    int gg = nl >> 5, j = nb * 32 + (nl & 31);
    int k = kt * 128 + ((cc ^ (nl & 7)) << 4) + e;
    float v;
    if (gg == 3) v = w_hh[(size_t)(2048 + j) * 1024 + k];
    else {
      int rr = gg * 1024 + j;
      v = w_ih[(size_t)rr * 1536 + 256 + k];
      if (gg < 2) v += w_hh[(size_t)rr * 1024 + k];
    }
    float sc = (gg >= 2) ? 4096.f : 2048.f;
    int wq = __float2int_rn(v * sc);
    wq = wq > 127 ? 127 : (wq < -127 ? -127 : wq);
    WcH3[i] = (char)wq;
  } else if (i < 5767168) {                // WcX3: [nb24][kt8][nl128][c8][e8], n=g*1024+j
    int q = i - 4194304;
    int blk = q >> 13;
    int nb = blk >> 3, kt = blk & 7;
    int r = q & 8191;
    int nl = r >> 6, cc = (r >> 3) & 7, e = r & 7;
    int gg = nb >> 3;                       // 0..2
    int j  = (nb & 7) * 128 + nl;
    int rr = gg * 1024 + j;
    int k = kt * 64 + ((cc ^ (nl & 7)) << 3) + e;
    float v = (k < 256) ? w_ih[(size_t)rr * 1536 + k]
                        : w_ih[(size_t)rr * 1536 + 1280 + (k - 256)];
    WcX3[q] = (bf16)v;
  } else if (i < 6029312) {                // Wgs
    int q = i - 5767168;
    int blk = q >> 13;
    int nb = blk >> 2, kt = blk & 3;
    int r = q & 8191;
    int nl = r >> 6, cc = (r >> 3) & 7, e = r & 7;
    int n = nb * 128 + nl;
    int k = kt * 64 + ((cc ^ (nl & 7)) << 3) + e;
    Wgs[q] = (bf16)w_gh[(size_t)n * 256 + k];
  } else if (i < 6033408) {                // bias4
    int q = i - 6029312;
    int gg = q >> 10, j = q & 1023;
    float v;
    if (gg == 0)      v = b_ih[j] + b_hh[j];
    else if (gg == 1) v = b_ih[1024 + j] + b_hh[1024 + j];
    else if (gg == 2) v = b_ih[2048 + j];
    else              v = b_hh[2048 + j];
    bias4[q] = v;
  }
}

// ---------------------------------------------------------------------------
// gammah: R10 double-buffered version (unchanged)
// ---------------------------------------------------------------------------
__global__ __launch_bounds__(256) void gammah_kernel(const bf16* __restrict__ Dbfs,
                                                     const bf16* __restrict__ Wgs,
                                                     const float* __restrict__ b_gh,
                                                     bf16* __restrict__ GH) {
  __shared__ char smem[65536];
  char* As = smem;
  char* Bs = smem + 32768;
  int tid = threadIdx.x, lane = tid & 63, wid = tid >> 6;
  int wr = wid >> 1, wc = wid & 1;
  int cpx = gridDim.x >> 3;
  int wg = (blockIdx.x & 7) * cpx + (blockIdx.x >> 3);
  int nb = wg & 7, mb = wg >> 3;

  const bf16* aA = Dbfs + ((size_t)(mb * 128 + wid * 8 + (lane >> 3))) * 256 + (lane & 7) * 8;
  const bf16* aB = Wgs + (size_t)nb * 4 * 8192 + wid * 512 + lane * 8;

  f32x4 acc[4][4];
#pragma unroll
  for (int a = 0; a < 4; ++a)
#pragma unroll
    for (int b = 0; b < 4; ++b)
#pragma unroll
      for (int q = 0; q < 4; ++q) acc[a][b][q] = 0.f;

#define GM_STAGE(buf, kt)                                                         \
  do {                                                                            \
    _Pragma("unroll")                                                             \
    for (int q = 0; q < 4; ++q)                                                   \
      GLL16(aA + q * (32 * 256) + (kt) * 64, As + (buf) * 16384 + (q * 4 + wid) * 1024); \
    _Pragma("unroll")                                                             \
    for (int q = 0; q < 4; ++q)                                                   \
      GLL16(aB + (size_t)(kt) * 8192 + q * 2048, Bs + (buf) * 16384 + (q * 4 + wid) * 1024); \
  } while (0)

  GM_STAGE(0, 0);
  __syncthreads();
  for (int kt = 0; kt < 4; ++kt) {
    const int cur = kt & 1;
    if (kt < 3) GM_STAGE(cur ^ 1, kt + 1);
#pragma unroll
    for (int kk = 0; kk < 2; ++kk) {
      int kb = kk * 64 + ((lane >> 4) << 4);
      bf16x8 af[4], bfr[4];
#pragma unroll
      for (int mf = 0; mf < 4; ++mf) {
        int row = wr * 64 + mf * 16 + (lane & 15);
        af[mf] = *(const bf16x8*)(As + cur * 16384 + (((row * 128 + kb)) ^ ((row & 7) << 4)));
      }
#pragma unroll
      for (int nf = 0; nf < 4; ++nf) {
        int nl = wc * 64 + nf * 16 + (lane & 15);
        bfr[nf] = *(const bf16x8*)(Bs + cur * 16384 + (((nl * 128 + kb)) ^ ((nl & 7) << 4)));
      }
#pragma unroll
      for (int mf = 0; mf < 4; ++mf)
#pragma unroll
        for (int nf = 0; nf < 4; ++nf)
          acc[mf][nf] = __builtin_amdgcn_mfma_f32_16x16x32_bf16(af[mf], bfr[nf], acc[mf][nf], 0, 0, 0);
    }
    __syncthreads();
  }
  char* ep = smem;
#pragma unroll
  for (int nf = 0; nf < 4; ++nf) {
    int col = wc * 64 + nf * 16 + (lane & 15);
    float bg = b_gh[nb * 128 + col];
#pragma unroll
    for (int mf = 0; mf < 4; ++mf)
#pragma unroll
      for (int reg = 0; reg < 4; ++reg) {
        int row = wr * 64 + mf * 16 + ((lane >> 4) << 2) + reg;
        int cph = ((col >> 3) ^ (((row >> 2) & 3) << 2));
        *(bf16*)(ep + row * 256 + (cph << 4) + (col & 7) * 2) =
            (bf16)__expf(-fmaxf(acc[mf][nf][reg] + bg, 0.f));
      }
  }
  __syncthreads();
#pragma unroll
  for (int p = 0; p < 8; ++p) {
    int idx = p * 256 + tid;
    int row = idx >> 4, c = idx & 15;
    int cph = c ^ (((row >> 2) & 3) << 2);
    bf16x8 v = *(const bf16x8*)(ep + row * 256 + (cph << 4));
    *(bf16x8*)(GH + (size_t)(mb * 128 + row) * 1024 + nb * 128 + c * 8) = v;
  }
}

// ---------------------------------------------------------------------------
// gix: unchanged from R10
// ---------------------------------------------------------------------------
__global__ __launch_bounds__(256) void gix_kernel(const bf16* __restrict__ XRs,
                                                  const bf16* __restrict__ WcX3,
                                                  bf16* __restrict__ Gi) {
  __shared__ char smem[65536];
  char* As = smem;
  char* Bs = smem + 32768;
  int tid = threadIdx.x, lane = tid & 63, wid = tid >> 6;
  int wr = wid >> 1, wc = wid & 1;
  int cpx = gridDim.x >> 3;
  int wg = (blockIdx.x & 7) * cpx + (blockIdx.x >> 3);
  int nb = wg % 24, mb = wg / 24;

  const bf16* aA = XRs + ((size_t)(mb * 128 + wid * 8 + (lane >> 3))) * 512 + (lane & 7) * 8;
  const bf16* aB = WcX3 + (size_t)nb * 8 * 8192 + wid * 512 + lane * 8;

  f32x4 acc[4][4];
#pragma unroll
  for (int a = 0; a < 4; ++a)
#pragma unroll
    for (int b = 0; b < 4; ++b)
#pragma unroll
      for (int q = 0; q < 4; ++q) acc[a][b][q] = 0.f;

#define GX_STAGE(buf, kt)                                                         \
  do {                                                                            \
    _Pragma("unroll")                                                             \
    for (int q = 0; q < 4; ++q)                                                   \
      GLL16(aA + q * (32 * 512) + (kt) * 64, As + (buf) * 16384 + (q * 4 + wid) * 1024); \
    _Pragma("unroll")                                                             \
    for (int q = 0; q < 4; ++q)                                                   \
      GLL16(aB + (size_t)(kt) * 8192 + q * 2048, Bs + (buf) * 16384 + (q * 4 + wid) * 1024); \
  } while (0)

  GX_STAGE(0, 0);
  __syncthreads();
  for (int kt = 0; kt < 8; ++kt) {
    const int cur = kt & 1;
    if (kt < 7) GX_STAGE(cur ^ 1, kt + 1);
#pragma unroll
    for (int kk = 0; kk < 2; ++kk) {
      int kb = kk * 64 + ((lane >> 4) << 4);
      bf16x8 af[4], bfr[4];
#pragma unroll
      for (int mf = 0; mf < 4; ++mf) {
        int row = wr * 64 + mf * 16 + (lane & 15);
        af[mf] = *(const bf16x8*)(As + cur * 16384 + (((row * 128 + kb)) ^ ((row & 7) << 4)));
      }
#pragma unroll
      for (int nf = 0; nf < 4; ++nf) {
        int nl = wc * 64 + nf * 16 + (lane & 15);
        bfr[nf] = *(const bf16x8*)(Bs + cur * 16384 + (((nl * 128 + kb)) ^ ((nl & 7) << 4)));
      }
#pragma unroll
      for (int mf = 0; mf < 4; ++mf)
#pragma unroll
        for (int nf = 0; nf < 4; ++nf)
          acc[mf][nf] = __builtin_amdgcn_mfma_f32_16x16x32_bf16(af[mf], bfr[nf], acc[mf][nf], 0, 0, 0);
    }
    __syncthreads();
  }
  char* ep = smem;
#pragma unroll
  for (int nf = 0; nf < 4; ++nf) {
    int col = wc * 64 + nf * 16 + (lane & 15);
#pragma unroll
    for (int mf = 0; mf < 4; ++mf)
#pragma unroll
      for (int reg = 0; reg < 4; ++reg) {
        int row = wr * 64 + mf * 16 + ((lane >> 4) << 2) + reg;
        int cph = ((col >> 3) ^ (((row >> 2) & 3) << 2));
        *(bf16*)(ep + row * 256 + (cph << 4) + (col & 7) * 2) = (bf16)acc[mf][nf][reg];
      }
  }
  __syncthreads();
  {
    int sl = mb >> 3, mbl = mb & 7;
    bf16* plane = Gi + (size_t)sl * 3145728 + (size_t)(nb >> 3) * 1048576 + (nb & 7) * 128;
#pragma unroll
    for (int p = 0; p < 8; ++p) {
      int idx = p * 256 + tid;
      int row = idx >> 4, c = idx & 15;
      int cph = c ^ (((row >> 2) & 3) << 2);
      bf16x8 v = *(const bf16x8*)(ep + row * 256 + (cph << 4));
      *(bf16x8*)(plane + (size_t)(mbl * 128 + row) * 1024 + c * 8) = v;
    }
  }
}

// ---------------------------------------------------------------------------
// step: single-plane i8 h-GEMM. 64x128 tile, 512 threads, 4x2 waves, grid 512.
// K=1024 in 8 iters of 128 bytes; mfma_i32_16x16x64_i8.
// LDS 48KB (A 2x8K, B 2x16K), 2-phase dbuf, fused GRU epilogue.
// ---------------------------------------------------------------------------
__global__ __launch_bounds__(512, 4) void step_kernel(
    const char* __restrict__ hbs, const float* __restrict__ hf,
    const char* __restrict__ WcH3, const float* __restrict__ bias4,
    const bf16* __restrict__ gi, const bf16* __restrict__ gh_next, int is_last,
    float* __restrict__ hf_next, char* __restrict__ hbs_next) {
  __shared__ char smem[49152];   // A [2][8192] @0, B [2][16384] @16384
  int tid = threadIdx.x, lane = tid & 63, wid = tid >> 6;
  int wr = wid >> 1, wc = wid & 1;
  int wg = ((blockIdx.x & 7) << 6) + (blockIdx.x >> 3);
  int mb = wg & 15, nb = wg >> 4;

  const char* aA = hbs + (size_t)(mb * 64 + (tid >> 3)) * 1024 + (tid & 7) * 16;
  const char* aB = WcH3 + (size_t)nb * 131072 + (tid >> 3) * 128 + (tid & 7) * 16;

  // ---- epilogue prefetch (hidden under the GEMM) ----
  int j = nb * 32 + wc * 16 + (lane & 15);
  bf16  grv[4], gzv[4], gnv[4], ghv[4];
  float hfv[4];
#pragma unroll
  for (int reg = 0; reg < 4; ++reg) {
    int brow = mb * 64 + wr * 16 + ((lane >> 4) << 2) + reg;
    size_t hb_ = (size_t)brow * 1024 + j;
    grv[reg] = gi[hb_];
    gzv[reg] = gi[1048576 + hb_];
    gnv[reg] = gi[2097152 + hb_];
    ghv[reg] = gh_next[hb_];
    hfv[reg] = hf[hb_];
  }

  i32x4 acc[4];
#pragma unroll
  for (int b = 0; b < 4; ++b)
#pragma unroll
    for (int q = 0; q < 4; ++q) acc[b][q] = 0;

#define ST_STAGE(buf, kt)                                                            \
  do {                                                                               \
    GLL16(aA + (kt) * 128,            smem + (buf) * 8192 + wid * 1024);             \
    GLL16(aB + (kt) * 16384,          smem + 16384 + (buf) * 16384 + wid * 1024);    \
    GLL16(aB + (kt) * 16384 + 8192,   smem + 16384 + (buf) * 16384 + 8192 + wid * 1024); \
  } while (0)

  ST_STAGE(0, 0);
  __syncthreads();
  for (int kt = 0; kt < 8; ++kt) {
    const int cur = kt & 1;
    if (kt < 7) ST_STAGE(cur ^ 1, kt + 1);
    const char* Ab = smem + cur * 8192;
    const char* Bb = smem + 16384 + cur * 16384;
#pragma unroll
    for (int kk = 0; kk < 2; ++kk) {
      int kb = kk * 64 + ((lane >> 4) << 4);   // byte offset within 128B row
      int row = wr * 16 + (lane & 15);
      i32x4 af = *(const i32x4*)(Ab + ((row * 128 + (kb ^ ((row & 7) << 4)))));
      i32x4 bfr[4];
#pragma unroll
      for (int g = 0; g < 4; ++g) {
        int nl = g * 32 + wc * 16 + (lane & 15);
        bfr[g] = *(const i32x4*)(Bb + ((nl * 128 + (kb ^ ((nl & 7) << 4)))));
      }
#pragma unroll
      for (int g = 0; g < 4; ++g)
        acc[g] = __builtin_amdgcn_mfma_i32_16x16x64_i8(af, bfr[g], acc[g], 0, 0, 0);
    }
    __syncthreads();
  }

  // fused GRU epilogue: preact = acc * ISC_g (+ Gi + bias)
  const float ISC_RZ = 3.814697265625e-06f;    // 1/(128*2048)
  const float ISC_N  = 1.9073486328125e-06f;   // 1/(128*4096)
  float br = bias4[j], bz = bias4[1024 + j], bn = bias4[2048 + j], bh = bias4[3072 + j];
#pragma unroll
  for (int reg = 0; reg < 4; ++reg) {
    int brow = mb * 64 + wr * 16 + ((lane >> 4) << 2) + reg;
    float pr  = (float)acc[0][reg] * ISC_RZ + (float)grv[reg] + br;
    float pz  = (float)acc[1][reg] * ISC_RZ + (float)gzv[reg] + bz;
    float pin = (float)acc[2][reg] * ISC_N  + (float)gnv[reg] + bn;
    float phn = (float)acc[3][reg] * ISC_N  + bh;
    float r = sigm(pr), z = sigm(pz);
    float nn = tanh_fast(pin + r * phn);
    float hnew = (1.f - z) * nn + z * hfv[reg];
    float gam = is_last ? 1.f : (float)ghv[reg];
    float hd = hnew * gam;
    hf_next[(size_t)brow * 1024 + j] = hd;
    int hi8 = __float2int_rn(hd * 128.f);
    hi8 = hi8 > 127 ? 127 : (hi8 < -127 ? -127 : hi8);
    hbs_next[(size_t)brow * 1024 + (j ^ ((brow & 7) << 4))] = (char)hi8;
  }
}

// ---------------------------------------------------------------------------
// classifier + softmax
// ---------------------------------------------------------------------------
__global__ void cls_kernel(const float* __restrict__ h, const float* __restrict__ w_cls,
                           const float* __restrict__ b_cls, float* __restrict__ out) {
  int wid = threadIdx.x >> 6, lane = threadIdx.x & 63;
  int b = blockIdx.x * 4 + wid;
  const float* hb = h + (size_t)b * 1024;
  float a0 = 0.f, a1 = 0.f;
#pragma unroll
  for (int e = 0; e < 16; ++e) {
    int i = e * 64 + lane;
    float hv = hb[i];
    a0 += hv * w_cls[i];
    a1 += hv * w_cls[1024 + i];
  }
  for (int off = 32; off; off >>= 1) {
    a0 += __shfl_down(a0, off);
    a1 += __shfl_down(a1, off);
  }
  if (lane == 0) {
    float l0 = a0 + b_cls[0], l1 = a1 + b_cls[1];
    float mx = fmaxf(l0, l1);
    float e0 = __expf(l0 - mx), e1 = __expf(l1 - mx);
    float s = e0 + e1;
    out[b * 2]     = e0 / s;
    out[b * 2 + 1] = e1 / s;
  }
}

// ---------------------------------------------------------------------------
extern "C" void kernel_launch(void* const* d_in, const int* in_sizes, int n_in,
                              void* d_out, int out_size, void* d_ws, size_t ws_size,
                              hipStream_t stream) {
  const float* X     = (const float*)d_in[0];
  const float* Msk   = (const float*)d_in[1];
  const float* D     = (const float*)d_in[2];
  const float* Mean  = (const float*)d_in[3];
  const float* L     = (const float*)d_in[4];
  const float* w_gh  = (const float*)d_in[5];
  const float* b_gh  = (const float*)d_in[6];
  const float* w_gx  = (const float*)d_in[7];
  const float* b_gx  = (const float*)d_in[8];
  const float* w_ih  = (const float*)d_in[9];
  const float* w_hh  = (const float*)d_in[10];
  const float* b_ih  = (const float*)d_in[11];
  const float* b_hh  = (const float*)d_in[12];
  const float* w_cls = (const float*)d_in[13];
  const float* b_cls = (const float*)d_in[14];

  char* w = (char*)d_ws;
  bf16*  XRs   = (bf16*)(w);
  bf16*  Dbfs  = (bf16*)(w + 16777216);
  bf16*  GH    = (bf16*)(w + 25690112);
  bf16*  WcX3  = (bf16*)(w + 61341696);
  char*  WcH3  = (char*)(w + 65536000);
  bf16*  Wgs   = (bf16*)(w + 73924608);
  float* bias4 = (float*)(w + 74448896);
  float* hf0   = (float*)(w + 74465280);
  float* hf1   = (float*)(w + 78659584);
  char*  hb0   = (char*)(w + 82853888);
  char*  hb1   = (char*)(w + 84951040);
  bf16*  Gi    = (bf16*)(w + 87048192);

  size_t base = 87048192;
  int GCH = 16;
  while (GCH > 1 && base + (size_t)GCH * 6291456ull > ws_size) GCH >>= 1;

  float* hfp[2] = {hf0, hf1};
  char*  hbp[2] = {hb0, hb1};

  hipMemsetAsync(hf0, 0, 4194304, stream);
  hipMemsetAsync(hb0, 0, 1048576, stream);
  wprep_kernel<<<23568, 256, 0, stream>>>(w_ih, w_hh, b_ih, b_hh, w_gh, WcH3, WcX3, Wgs, bias4);

  int t = 0;
  for (int c = 0; c < 4; ++c) {
    int nsl = (c < 3) ? 17 : 16;
    prep_kernel<<<nsl * 1024, 256, 0, stream>>>(X, Msk, D, Mean, L, w_gx, b_gx, XRs, Dbfs, c, nsl);
    gammah_kernel<<<nsl * 64, 256, 0, stream>>>(Dbfs, Wgs, b_gh, GH);
    for (int sub = 0; sub < 16 / GCH; ++sub) {
      gix_kernel<<<GCH * 192, 256, 0, stream>>>(XRs + (size_t)sub * GCH * 524288, WcX3, Gi);
      for (int tl2 = 0; tl2 < GCH; ++tl2, ++t) {
        int tl = sub * GCH + tl2;
        int cur = t & 1, nxt = cur ^ 1;
        step_kernel<<<512, 512, 0, stream>>>(
            hbp[cur], hfp[cur], WcH3, bias4,
            Gi + (size_t)tl2 * 3145728, GH + (size_t)(tl + 1) * 1048576,
            (t == 63) ? 1 : 0, hfp[nxt], hbp[nxt]);
      }
    }
  }
  cls_kernel<<<256, 256, 0, stream>>>(hfp[0], w_cls, b_cls, (float*)d_out);
}

// Round 15
// 1126.318 us; speedup vs baseline: 1.2700x; 1.0213x over previous
//
#include <hip/hip_runtime.h>

using bf16   = __bf16;
using bf16x8 = __bf16 __attribute__((ext_vector_type(8)));
using f32x4  = float  __attribute__((ext_vector_type(4)));
using i32x4  = int    __attribute__((ext_vector_type(4)));

// B=1024, T=64, F=256, H=1024, C=2
// ws layout: identical to R14. WcH3 i8, hb i8 single-plane, Gi gate-planes bf16.

__device__ __forceinline__ float sigm(float x) { return 1.f / (1.f + __expf(-x)); }
__device__ __forceinline__ float tanh_fast(float x) {
  float e = __expf(2.f * x);
  return 1.f - 2.f / (e + 1.f);
}

#define GLL16(gsrc, ldst)                                                              \
  __builtin_amdgcn_global_load_lds((const __attribute__((address_space(1))) void*)(gsrc), \
                                   (__attribute__((address_space(3))) void*)(ldst), 16, 0, 0)

// ---------------------------------------------------------------------------
// prep: pre-swizzled XRs ([xr|m], f XOR (b&7)<<3) and Dbfs   (unchanged)
// ---------------------------------------------------------------------------
__global__ void prep_kernel(const float* __restrict__ X, const float* __restrict__ Msk,
                            const float* __restrict__ D, const float* __restrict__ Mean,
                            const float* __restrict__ L, const float* __restrict__ w_gx,
                            const float* __restrict__ b_gx,
                            bf16* __restrict__ XRs, bf16* __restrict__ Dbfs,
                            int c, int nsl) {
  int i = blockIdx.x * 256 + threadIdx.x;
  if (i >= (nsl << 18)) return;
  int f = i & 255, b = (i >> 8) & 1023, tl = i >> 18;
  int t = c * 16 + tl;
  size_t g = ((size_t)b << 14) + ((size_t)t << 8) + f;
  float d = D[g];
  int fs = f ^ ((b & 7) << 3);
  int row = tl * 1024 + b;
  Dbfs[(size_t)row * 256 + fs] = (bf16)d;
  float gx = __expf(-fmaxf(d * w_gx[f] + b_gx[f], 0.f));
  float xh = gx * L[g] + (1.f - gx) * Mean[(size_t)b * 256 + f];
  float m  = Msk[g];
  float xr = m * X[g] + (1.f - m) * xh;
  if (tl < 16) {
    size_t xo = (size_t)row * 512;
    XRs[xo + fs]       = (bf16)xr;
    XRs[xo + 256 + fs] = (bf16)m;
  }
}

// ---------------------------------------------------------------------------
// wprep: WcH3 i8 with per-gate scales (unchanged from R14)
// ---------------------------------------------------------------------------
__global__ void wprep_kernel(const float* __restrict__ w_ih, const float* __restrict__ w_hh,
                             const float* __restrict__ b_ih, const float* __restrict__ b_hh,
                             const float* __restrict__ w_gh,
                             char* __restrict__ WcH3, bf16* __restrict__ WcX3,
                             bf16* __restrict__ Wgs, float* __restrict__ bias4) {
  int i = blockIdx.x * 256 + threadIdx.x;
  if (i < 4194304) {                       // WcH3 i8: [nb32][kt8][nl128][cc8][e16]
    int nb = i >> 17;
    int rem = i & 131071;
    int kt = rem >> 14;
    int r2 = rem & 16383;
    int nl = r2 >> 7, bb = r2 & 127;
    int cc = bb >> 4, e = bb & 15;
    int gg = nl >> 5, j = nb * 32 + (nl & 31);
    int k = kt * 128 + ((cc ^ (nl & 7)) << 4) + e;
    float v;
    if (gg == 3) v = w_hh[(size_t)(2048 + j) * 1024 + k];
    else {
      int rr = gg * 1024 + j;
      v = w_ih[(size_t)rr * 1536 + 256 + k];
      if (gg < 2) v += w_hh[(size_t)rr * 1024 + k];
    }
    float sc = (gg >= 2) ? 4096.f : 2048.f;
    int wq = __float2int_rn(v * sc);
    wq = wq > 127 ? 127 : (wq < -127 ? -127 : wq);
    WcH3[i] = (char)wq;
  } else if (i < 5767168) {                // WcX3: [nb24][kt8][nl128][c8][e8], n=g*1024+j
    int q = i - 4194304;
    int blk = q >> 13;
    int nb = blk >> 3, kt = blk & 7;
    int r = q & 8191;
    int nl = r >> 6, cc = (r >> 3) & 7, e = r & 7;
    int gg = nb >> 3;                       // 0..2
    int j  = (nb & 7) * 128 + nl;
    int rr = gg * 1024 + j;
    int k = kt * 64 + ((cc ^ (nl & 7)) << 3) + e;
    float v = (k < 256) ? w_ih[(size_t)rr * 1536 + k]
                        : w_ih[(size_t)rr * 1536 + 1280 + (k - 256)];
    WcX3[q] = (bf16)v;
  } else if (i < 6029312) {                // Wgs
    int q = i - 5767168;
    int blk = q >> 13;
    int nb = blk >> 2, kt = blk & 3;
    int r = q & 8191;
    int nl = r >> 6, cc = (r >> 3) & 7, e = r & 7;
    int n = nb * 128 + nl;
    int k = kt * 64 + ((cc ^ (nl & 7)) << 3) + e;
    Wgs[q] = (bf16)w_gh[(size_t)n * 256 + k];
  } else if (i < 6033408) {                // bias4
    int q = i - 6029312;
    int gg = q >> 10, j = q & 1023;
    float v;
    if (gg == 0)      v = b_ih[j] + b_hh[j];
    else if (gg == 1) v = b_ih[1024 + j] + b_hh[1024 + j];
    else if (gg == 2) v = b_ih[2048 + j];
    else              v = b_hh[2048 + j];
    bias4[q] = v;
  }
}

// ---------------------------------------------------------------------------
// combo: blocks [0, gxblocks) = gix role (R14 verbatim);
//        blocks [gxblocks, +nsl*64) = gammah role (R14 verbatim).
// Both roles: 256 threads, 64KB LDS, 2 blocks/CU. gxblocks divisible by 8
// so each role's XCD swizzle (bid&7) is preserved.
// ---------------------------------------------------------------------------
__global__ __launch_bounds__(256) void combo_kernel(
    const bf16* __restrict__ XRs, const bf16* __restrict__ WcX3,
    bf16* __restrict__ Gi, int gxblocks,
    const bf16* __restrict__ Dbfs, const bf16* __restrict__ Wgs,
    const float* __restrict__ b_gh, bf16* __restrict__ GH, int gmblocks) {
  __shared__ char smem[65536];
  char* As = smem;
  char* Bs = smem + 32768;
  int bid = blockIdx.x;
  int tid = threadIdx.x, lane = tid & 63, wid = tid >> 6;
  int wr = wid >> 1, wc = wid & 1;

  if (bid < gxblocks) {
    // ------------------------- gix role -------------------------
    int cpx = gxblocks >> 3;
    int wg = (bid & 7) * cpx + (bid >> 3);
    int nb = wg % 24, mb = wg / 24;

    const bf16* aA = XRs + ((size_t)(mb * 128 + wid * 8 + (lane >> 3))) * 512 + (lane & 7) * 8;
    const bf16* aB = WcX3 + (size_t)nb * 8 * 8192 + wid * 512 + lane * 8;

    f32x4 acc[4][4];
#pragma unroll
    for (int a = 0; a < 4; ++a)
#pragma unroll
      for (int b = 0; b < 4; ++b)
#pragma unroll
        for (int q = 0; q < 4; ++q) acc[a][b][q] = 0.f;

#define GX_STAGE(buf, kt)                                                         \
  do {                                                                            \
    _Pragma("unroll")                                                             \
    for (int q = 0; q < 4; ++q)                                                   \
      GLL16(aA + q * (32 * 512) + (kt) * 64, As + (buf) * 16384 + (q * 4 + wid) * 1024); \
    _Pragma("unroll")                                                             \
    for (int q = 0; q < 4; ++q)                                                   \
      GLL16(aB + (size_t)(kt) * 8192 + q * 2048, Bs + (buf) * 16384 + (q * 4 + wid) * 1024); \
  } while (0)

    GX_STAGE(0, 0);
    __syncthreads();
    for (int kt = 0; kt < 8; ++kt) {
      const int cur = kt & 1;
      if (kt < 7) GX_STAGE(cur ^ 1, kt + 1);
#pragma unroll
      for (int kk = 0; kk < 2; ++kk) {
        int kb = kk * 64 + ((lane >> 4) << 4);
        bf16x8 af[4], bfr[4];
#pragma unroll
        for (int mf = 0; mf < 4; ++mf) {
          int row = wr * 64 + mf * 16 + (lane & 15);
          af[mf] = *(const bf16x8*)(As + cur * 16384 + (((row * 128 + kb)) ^ ((row & 7) << 4)));
        }
#pragma unroll
        for (int nf = 0; nf < 4; ++nf) {
          int nl = wc * 64 + nf * 16 + (lane & 15);
          bfr[nf] = *(const bf16x8*)(Bs + cur * 16384 + (((nl * 128 + kb)) ^ ((nl & 7) << 4)));
        }
#pragma unroll
        for (int mf = 0; mf < 4; ++mf)
#pragma unroll
          for (int nf = 0; nf < 4; ++nf)
            acc[mf][nf] = __builtin_amdgcn_mfma_f32_16x16x32_bf16(af[mf], bfr[nf], acc[mf][nf], 0, 0, 0);
      }
      __syncthreads();
    }
    char* ep = smem;
#pragma unroll
    for (int nf = 0; nf < 4; ++nf) {
      int col = wc * 64 + nf * 16 + (lane & 15);
#pragma unroll
      for (int mf = 0; mf < 4; ++mf)
#pragma unroll
        for (int reg = 0; reg < 4; ++reg) {
          int row = wr * 64 + mf * 16 + ((lane >> 4) << 2) + reg;
          int cph = ((col >> 3) ^ (((row >> 2) & 3) << 2));
          *(bf16*)(ep + row * 256 + (cph << 4) + (col & 7) * 2) = (bf16)acc[mf][nf][reg];
        }
    }
    __syncthreads();
    {
      int sl = mb >> 3, mbl = mb & 7;
      bf16* plane = Gi + (size_t)sl * 3145728 + (size_t)(nb >> 3) * 1048576 + (nb & 7) * 128;
#pragma unroll
      for (int p = 0; p < 8; ++p) {
        int idx = p * 256 + tid;
        int row = idx >> 4, c = idx & 15;
        int cph = c ^ (((row >> 2) & 3) << 2);
        bf16x8 v = *(const bf16x8*)(ep + row * 256 + (cph << 4));
        *(bf16x8*)(plane + (size_t)(mbl * 128 + row) * 1024 + c * 8) = v;
      }
    }
    return;
  }

  // ------------------------- gammah role -------------------------
  {
    int lbid = bid - gxblocks;
    int cpx = gmblocks >> 3;
    int wg = (lbid & 7) * cpx + (lbid >> 3);
    int nb = wg & 7, mb = wg >> 3;

    const bf16* aA = Dbfs + ((size_t)(mb * 128 + wid * 8 + (lane >> 3))) * 256 + (lane & 7) * 8;
    const bf16* aB = Wgs + (size_t)nb * 4 * 8192 + wid * 512 + lane * 8;

    f32x4 acc[4][4];
#pragma unroll
    for (int a = 0; a < 4; ++a)
#pragma unroll
      for (int b = 0; b < 4; ++b)
#pragma unroll
        for (int q = 0; q < 4; ++q) acc[a][b][q] = 0.f;

#define GM_STAGE(buf, kt)                                                         \
  do {                                                                            \
    _Pragma("unroll")                                                             \
    for (int q = 0; q < 4; ++q)                                                   \
      GLL16(aA + q * (32 * 256) + (kt) * 64, As + (buf) * 16384 + (q * 4 + wid) * 1024); \
    _Pragma("unroll")                                                             \
    for (int q = 0; q < 4; ++q)                                                   \
      GLL16(aB + (size_t)(kt) * 8192 + q * 2048, Bs + (buf) * 16384 + (q * 4 + wid) * 1024); \
  } while (0)

    GM_STAGE(0, 0);
    __syncthreads();
    for (int kt = 0; kt < 4; ++kt) {
      const int cur = kt & 1;
      if (kt < 3) GM_STAGE(cur ^ 1, kt + 1);
#pragma unroll
      for (int kk = 0; kk < 2; ++kk) {
        int kb = kk * 64 + ((lane >> 4) << 4);
        bf16x8 af[4], bfr[4];
#pragma unroll
        for (int mf = 0; mf < 4; ++mf) {
          int row = wr * 64 + mf * 16 + (lane & 15);
          af[mf] = *(const bf16x8*)(As + cur * 16384 + (((row * 128 + kb)) ^ ((row & 7) << 4)));
        }
#pragma unroll
        for (int nf = 0; nf < 4; ++nf) {
          int nl = wc * 64 + nf * 16 + (lane & 15);
          bfr[nf] = *(const bf16x8*)(Bs + cur * 16384 + (((nl * 128 + kb)) ^ ((nl & 7) << 4)));
        }
#pragma unroll
        for (int mf = 0; mf < 4; ++mf)
#pragma unroll
          for (int nf = 0; nf < 4; ++nf)
            acc[mf][nf] = __builtin_amdgcn_mfma_f32_16x16x32_bf16(af[mf], bfr[nf], acc[mf][nf], 0, 0, 0);
      }
      __syncthreads();
    }
    char* ep = smem;
#pragma unroll
    for (int nf = 0; nf < 4; ++nf) {
      int col = wc * 64 + nf * 16 + (lane & 15);
      float bg = b_gh[nb * 128 + col];
#pragma unroll
      for (int mf = 0; mf < 4; ++mf)
#pragma unroll
        for (int reg = 0; reg < 4; ++reg) {
          int row = wr * 64 + mf * 16 + ((lane >> 4) << 2) + reg;
          int cph = ((col >> 3) ^ (((row >> 2) & 3) << 2));
          *(bf16*)(ep + row * 256 + (cph << 4) + (col & 7) * 2) =
              (bf16)__expf(-fmaxf(acc[mf][nf][reg] + bg, 0.f));
        }
    }
    __syncthreads();
#pragma unroll
    for (int p = 0; p < 8; ++p) {
      int idx = p * 256 + tid;
      int row = idx >> 4, c = idx & 15;
      int cph = c ^ (((row >> 2) & 3) << 2);
      bf16x8 v = *(const bf16x8*)(ep + row * 256 + (cph << 4));
      *(bf16x8*)(GH + (size_t)(mb * 128 + row) * 1024 + nb * 128 + c * 8) = v;
    }
  }
}

// ---------------------------------------------------------------------------
// step: single-plane i8 h-GEMM (R14 verbatim)
// ---------------------------------------------------------------------------
__global__ __launch_bounds__(512, 4) void step_kernel(
    const char* __restrict__ hbs, const float* __restrict__ hf,
    const char* __restrict__ WcH3, const float* __restrict__ bias4,
    const bf16* __restrict__ gi, const bf16* __restrict__ gh_next, int is_last,
    float* __restrict__ hf_next, char* __restrict__ hbs_next) {
  __shared__ char smem[49152];   // A [2][8192] @0, B [2][16384] @16384
  int tid = threadIdx.x, lane = tid & 63, wid = tid >> 6;
  int wr = wid >> 1, wc = wid & 1;
  int wg = ((blockIdx.x & 7) << 6) + (blockIdx.x >> 3);
  int mb = wg & 15, nb = wg >> 4;

  const char* aA = hbs + (size_t)(mb * 64 + (tid >> 3)) * 1024 + (tid & 7) * 16;
  const char* aB = WcH3 + (size_t)nb * 131072 + (tid >> 3) * 128 + (tid & 7) * 16;

  int j = nb * 32 + wc * 16 + (lane & 15);
  bf16  grv[4], gzv[4], gnv[4], ghv[4];
  float hfv[4];
#pragma unroll
  for (int reg = 0; reg < 4; ++reg) {
    int brow = mb * 64 + wr * 16 + ((lane >> 4) << 2) + reg;
    size_t hb_ = (size_t)brow * 1024 + j;
    grv[reg] = gi[hb_];
    gzv[reg] = gi[1048576 + hb_];
    gnv[reg] = gi[2097152 + hb_];
    ghv[reg] = gh_next[hb_];
    hfv[reg] = hf[hb_];
  }

  i32x4 acc[4];
#pragma unroll
  for (int b = 0; b < 4; ++b)
#pragma unroll
    for (int q = 0; q < 4; ++q) acc[b][q] = 0;

#define ST_STAGE(buf, kt)                                                            \
  do {                                                                               \
    GLL16(aA + (kt) * 128,            smem + (buf) * 8192 + wid * 1024);             \
    GLL16(aB + (kt) * 16384,          smem + 16384 + (buf) * 16384 + wid * 1024);    \
    GLL16(aB + (kt) * 16384 + 8192,   smem + 16384 + (buf) * 16384 + 8192 + wid * 1024); \
  } while (0)

  ST_STAGE(0, 0);
  __syncthreads();
  for (int kt = 0; kt < 8; ++kt) {
    const int cur = kt & 1;
    if (kt < 7) ST_STAGE(cur ^ 1, kt + 1);
    const char* Ab = smem + cur * 8192;
    const char* Bb = smem + 16384 + cur * 16384;
#pragma unroll
    for (int kk = 0; kk < 2; ++kk) {
      int kb = kk * 64 + ((lane >> 4) << 4);
      int row = wr * 16 + (lane & 15);
      i32x4 af = *(const i32x4*)(Ab + ((row * 128 + (kb ^ ((row & 7) << 4)))));
      i32x4 bfr[4];
#pragma unroll
      for (int g = 0; g < 4; ++g) {
        int nl = g * 32 + wc * 16 + (lane & 15);
        bfr[g] = *(const i32x4*)(Bb + ((nl * 128 + (kb ^ ((nl & 7) << 4)))));
      }
#pragma unroll
      for (int g = 0; g < 4; ++g)
        acc[g] = __builtin_amdgcn_mfma_i32_16x16x64_i8(af, bfr[g], acc[g], 0, 0, 0);
    }
    __syncthreads();
  }

  const float ISC_RZ = 3.814697265625e-06f;    // 1/(128*2048)
  const float ISC_N  = 1.9073486328125e-06f;   // 1/(128*4096)
  float br = bias4[j], bz = bias4[1024 + j], bn = bias4[2048 + j], bh = bias4[3072 + j];
#pragma unroll
  for (int reg = 0; reg < 4; ++reg) {
    int brow = mb * 64 + wr * 16 + ((lane >> 4) << 2) + reg;
    float pr  = (float)acc[0][reg] * ISC_RZ + (float)grv[reg] + br;
    float pz  = (float)acc[1][reg] * ISC_RZ + (float)gzv[reg] + bz;
    float pin = (float)acc[2][reg] * ISC_N  + (float)gnv[reg] + bn;
    float phn = (float)acc[3][reg] * ISC_N  + bh;
    float r = sigm(pr), z = sigm(pz);
    float nn = tanh_fast(pin + r * phn);
    float hnew = (1.f - z) * nn + z * hfv[reg];
    float gam = is_last ? 1.f : (float)ghv[reg];
    float hd = hnew * gam;
    hf_next[(size_t)brow * 1024 + j] = hd;
    int hi8 = __float2int_rn(hd * 128.f);
    hi8 = hi8 > 127 ? 127 : (hi8 < -127 ? -127 : hi8);
    hbs_next[(size_t)brow * 1024 + (j ^ ((brow & 7) << 4))] = (char)hi8;
  }
}

// ---------------------------------------------------------------------------
// classifier + softmax
// ---------------------------------------------------------------------------
__global__ void cls_kernel(const float* __restrict__ h, const float* __restrict__ w_cls,
                           const float* __restrict__ b_cls, float* __restrict__ out) {
  int wid = threadIdx.x >> 6, lane = threadIdx.x & 63;
  int b = blockIdx.x * 4 + wid;
  const float* hb = h + (size_t)b * 1024;
  float a0 = 0.f, a1 = 0.f;
#pragma unroll
  for (int e = 0; e < 16; ++e) {
    int i = e * 64 + lane;
    float hv = hb[i];
    a0 += hv * w_cls[i];
    a1 += hv * w_cls[1024 + i];
  }
  for (int off = 32; off; off >>= 1) {
    a0 += __shfl_down(a0, off);
    a1 += __shfl_down(a1, off);
  }
  if (lane == 0) {
    float l0 = a0 + b_cls[0], l1 = a1 + b_cls[1];
    float mx = fmaxf(l0, l1);
    float e0 = __expf(l0 - mx), e1 = __expf(l1 - mx);
    float s = e0 + e1;
    out[b * 2]     = e0 / s;
    out[b * 2 + 1] = e1 / s;
  }
}

// ---------------------------------------------------------------------------
extern "C" void kernel_launch(void* const* d_in, const int* in_sizes, int n_in,
                              void* d_out, int out_size, void* d_ws, size_t ws_size,
                              hipStream_t stream) {
  const float* X     = (const float*)d_in[0];
  const float* Msk   = (const float*)d_in[1];
  const float* D     = (const float*)d_in[2];
  const float* Mean  = (const float*)d_in[3];
  const float* L     = (const float*)d_in[4];
  const float* w_gh  = (const float*)d_in[5];
  const float* b_gh  = (const float*)d_in[6];
  const float* w_gx  = (const float*)d_in[7];
  const float* b_gx  = (const float*)d_in[8];
  const float* w_ih  = (const float*)d_in[9];
  const float* w_hh  = (const float*)d_in[10];
  const float* b_ih  = (const float*)d_in[11];
  const float* b_hh  = (const float*)d_in[12];
  const float* w_cls = (const float*)d_in[13];
  const float* b_cls = (const float*)d_in[14];

  char* w = (char*)d_ws;
  bf16*  XRs   = (bf16*)(w);
  bf16*  Dbfs  = (bf16*)(w + 16777216);
  bf16*  GH    = (bf16*)(w + 25690112);
  bf16*  WcX3  = (bf16*)(w + 61341696);
  char*  WcH3  = (char*)(w + 65536000);
  bf16*  Wgs   = (bf16*)(w + 73924608);
  float* bias4 = (float*)(w + 74448896);
  float* hf0   = (float*)(w + 74465280);
  float* hf1   = (float*)(w + 78659584);
  char*  hb0   = (char*)(w + 82853888);
  char*  hb1   = (char*)(w + 84951040);
  bf16*  Gi    = (bf16*)(w + 87048192);

  size_t base = 87048192;
  int GCH = 16;
  while (GCH > 1 && base + (size_t)GCH * 6291456ull > ws_size) GCH >>= 1;

  float* hfp[2] = {hf0, hf1};
  char*  hbp[2] = {hb0, hb1};

  hipMemsetAsync(hf0, 0, 4194304, stream);
  hipMemsetAsync(hb0, 0, 1048576, stream);
  wprep_kernel<<<23568, 256, 0, stream>>>(w_ih, w_hh, b_ih, b_hh, w_gh, WcH3, WcX3, Wgs, bias4);

  int t = 0;
  for (int c = 0; c < 4; ++c) {
    int nsl = (c < 3) ? 17 : 16;
    prep_kernel<<<nsl * 1024, 256, 0, stream>>>(X, Msk, D, Mean, L, w_gx, b_gx, XRs, Dbfs, c, nsl);
    for (int sub = 0; sub < 16 / GCH; ++sub) {
      int gxblocks = GCH * 192;
      int nsl2 = (sub == 0) ? nsl : 0;     // gammah once per chunk, fused with first gix
      combo_kernel<<<gxblocks + nsl2 * 64, 256, 0, stream>>>(
          XRs + (size_t)sub * GCH * 524288, WcX3, Gi, gxblocks,
          Dbfs, Wgs, b_gh, GH, nsl2 * 64);
      for (int tl2 = 0; tl2 < GCH; ++tl2, ++t) {
        int tl = sub * GCH + tl2;
        int cur = t & 1, nxt = cur ^ 1;
        step_kernel<<<512, 512, 0, stream>>>(
            hbp[cur], hfp[cur], WcH3, bias4,
            Gi + (size_t)tl2 * 3145728, GH + (size_t)(tl + 1) * 1048576,
            (t == 63) ? 1 : 0, hfp[nxt], hbp[nxt]);
      }
    }
  }
  cls_kernel<<<256, 256, 0, stream>>>(hfp[0], w_cls, b_cls, (float*)d_out);
}

// Round 16
// 1125.224 us; speedup vs baseline: 1.2712x; 1.0010x over previous
//
#include <hip/hip_runtime.h>

using bf16   = __bf16;
using bf16x8 = __bf16 __attribute__((ext_vector_type(8)));
using f32x4  = float  __attribute__((ext_vector_type(4)));
using i32x4  = int    __attribute__((ext_vector_type(4)));

// B=1024, T=64, F=256, H=1024, C=2
// ws layout: as R14/R15, except hf0/hf1 now bf16 (2MB used of 4MB regions).

__device__ __forceinline__ float sigm(float x) { return 1.f / (1.f + __expf(-x)); }
__device__ __forceinline__ float tanh_fast(float x) {
  float e = __expf(2.f * x);
  return 1.f - 2.f / (e + 1.f);
}

#define GLL16(gsrc, ldst)                                                              \
  __builtin_amdgcn_global_load_lds((const __attribute__((address_space(1))) void*)(gsrc), \
                                   (__attribute__((address_space(3))) void*)(ldst), 16, 0, 0)

// ---------------------------------------------------------------------------
// prep: pre-swizzled XRs ([xr|m], f XOR (b&7)<<3) and Dbfs   (unchanged)
// ---------------------------------------------------------------------------
__global__ void prep_kernel(const float* __restrict__ X, const float* __restrict__ Msk,
                            const float* __restrict__ D, const float* __restrict__ Mean,
                            const float* __restrict__ L, const float* __restrict__ w_gx,
                            const float* __restrict__ b_gx,
                            bf16* __restrict__ XRs, bf16* __restrict__ Dbfs,
                            int c, int nsl) {
  int i = blockIdx.x * 256 + threadIdx.x;
  if (i >= (nsl << 18)) return;
  int f = i & 255, b = (i >> 8) & 1023, tl = i >> 18;
  int t = c * 16 + tl;
  size_t g = ((size_t)b << 14) + ((size_t)t << 8) + f;
  float d = D[g];
  int fs = f ^ ((b & 7) << 3);
  int row = tl * 1024 + b;
  Dbfs[(size_t)row * 256 + fs] = (bf16)d;
  float gx = __expf(-fmaxf(d * w_gx[f] + b_gx[f], 0.f));
  float xh = gx * L[g] + (1.f - gx) * Mean[(size_t)b * 256 + f];
  float m  = Msk[g];
  float xr = m * X[g] + (1.f - m) * xh;
  if (tl < 16) {
    size_t xo = (size_t)row * 512;
    XRs[xo + fs]       = (bf16)xr;
    XRs[xo + 256 + fs] = (bf16)m;
  }
}

// ---------------------------------------------------------------------------
// wprep: WcH3 i8 with per-gate scales (unchanged from R14)
// ---------------------------------------------------------------------------
__global__ void wprep_kernel(const float* __restrict__ w_ih, const float* __restrict__ w_hh,
                             const float* __restrict__ b_ih, const float* __restrict__ b_hh,
                             const float* __restrict__ w_gh,
                             char* __restrict__ WcH3, bf16* __restrict__ WcX3,
                             bf16* __restrict__ Wgs, float* __restrict__ bias4) {
  int i = blockIdx.x * 256 + threadIdx.x;
  if (i < 4194304) {                       // WcH3 i8: [nb32][kt8][nl128][cc8][e16]
    int nb = i >> 17;
    int rem = i & 131071;
    int kt = rem >> 14;
    int r2 = rem & 16383;
    int nl = r2 >> 7, bb = r2 & 127;
    int cc = bb >> 4, e = bb & 15;
    int gg = nl >> 5, j = nb * 32 + (nl & 31);
    int k = kt * 128 + ((cc ^ (nl & 7)) << 4) + e;
    float v;
    if (gg == 3) v = w_hh[(size_t)(2048 + j) * 1024 + k];
    else {
      int rr = gg * 1024 + j;
      v = w_ih[(size_t)rr * 1536 + 256 + k];
      if (gg < 2) v += w_hh[(size_t)rr * 1024 + k];
    }
    float sc = (gg >= 2) ? 4096.f : 2048.f;
    int wq = __float2int_rn(v * sc);
    wq = wq > 127 ? 127 : (wq < -127 ? -127 : wq);
    WcH3[i] = (char)wq;
  } else if (i < 5767168) {                // WcX3: [nb24][kt8][nl128][c8][e8], n=g*1024+j
    int q = i - 4194304;
    int blk = q >> 13;
    int nb = blk >> 3, kt = blk & 7;
    int r = q & 8191;
    int nl = r >> 6, cc = (r >> 3) & 7, e = r & 7;
    int gg = nb >> 3;                       // 0..2
    int j  = (nb & 7) * 128 + nl;
    int rr = gg * 1024 + j;
    int k = kt * 64 + ((cc ^ (nl & 7)) << 3) + e;
    float v = (k < 256) ? w_ih[(size_t)rr * 1536 + k]
                        : w_ih[(size_t)rr * 1536 + 1280 + (k - 256)];
    WcX3[q] = (bf16)v;
  } else if (i < 6029312) {                // Wgs
    int q = i - 5767168;
    int blk = q >> 13;
    int nb = blk >> 2, kt = blk & 3;
    int r = q & 8191;
    int nl = r >> 6, cc = (r >> 3) & 7, e = r & 7;
    int n = nb * 128 + nl;
    int k = kt * 64 + ((cc ^ (nl & 7)) << 3) + e;
    Wgs[q] = (bf16)w_gh[(size_t)n * 256 + k];
  } else if (i < 6033408) {                // bias4
    int q = i - 6029312;
    int gg = q >> 10, j = q & 1023;
    float v;
    if (gg == 0)      v = b_ih[j] + b_hh[j];
    else if (gg == 1) v = b_ih[1024 + j] + b_hh[1024 + j];
    else if (gg == 2) v = b_ih[2048 + j];
    else              v = b_hh[2048 + j];
    bias4[q] = v;
  }
}

// ---------------------------------------------------------------------------
// combo: gix role + gammah role (R15 structure); Gi/GH stores non-temporal
// ---------------------------------------------------------------------------
__global__ __launch_bounds__(256) void combo_kernel(
    const bf16* __restrict__ XRs, const bf16* __restrict__ WcX3,
    bf16* __restrict__ Gi, int gxblocks,
    const bf16* __restrict__ Dbfs, const bf16* __restrict__ Wgs,
    const float* __restrict__ b_gh, bf16* __restrict__ GH, int gmblocks) {
  __shared__ char smem[65536];
  char* As = smem;
  char* Bs = smem + 32768;
  int bid = blockIdx.x;
  int tid = threadIdx.x, lane = tid & 63, wid = tid >> 6;
  int wr = wid >> 1, wc = wid & 1;

  if (bid < gxblocks) {
    // ------------------------- gix role -------------------------
    int cpx = gxblocks >> 3;
    int wg = (bid & 7) * cpx + (bid >> 3);
    int nb = wg % 24, mb = wg / 24;

    const bf16* aA = XRs + ((size_t)(mb * 128 + wid * 8 + (lane >> 3))) * 512 + (lane & 7) * 8;
    const bf16* aB = WcX3 + (size_t)nb * 8 * 8192 + wid * 512 + lane * 8;

    f32x4 acc[4][4];
#pragma unroll
    for (int a = 0; a < 4; ++a)
#pragma unroll
      for (int b = 0; b < 4; ++b)
#pragma unroll
        for (int q = 0; q < 4; ++q) acc[a][b][q] = 0.f;

#define GX_STAGE(buf, kt)                                                         \
  do {                                                                            \
    _Pragma("unroll")                                                             \
    for (int q = 0; q < 4; ++q)                                                   \
      GLL16(aA + q * (32 * 512) + (kt) * 64, As + (buf) * 16384 + (q * 4 + wid) * 1024); \
    _Pragma("unroll")                                                             \
    for (int q = 0; q < 4; ++q)                                                   \
      GLL16(aB + (size_t)(kt) * 8192 + q * 2048, Bs + (buf) * 16384 + (q * 4 + wid) * 1024); \
  } while (0)

    GX_STAGE(0, 0);
    __syncthreads();
    for (int kt = 0; kt < 8; ++kt) {
      const int cur = kt & 1;
      if (kt < 7) GX_STAGE(cur ^ 1, kt + 1);
#pragma unroll
      for (int kk = 0; kk < 2; ++kk) {
        int kb = kk * 64 + ((lane >> 4) << 4);
        bf16x8 af[4], bfr[4];
#pragma unroll
        for (int mf = 0; mf < 4; ++mf) {
          int row = wr * 64 + mf * 16 + (lane & 15);
          af[mf] = *(const bf16x8*)(As + cur * 16384 + (((row * 128 + kb)) ^ ((row & 7) << 4)));
        }
#pragma unroll
        for (int nf = 0; nf < 4; ++nf) {
          int nl = wc * 64 + nf * 16 + (lane & 15);
          bfr[nf] = *(const bf16x8*)(Bs + cur * 16384 + (((nl * 128 + kb)) ^ ((nl & 7) << 4)));
        }
#pragma unroll
        for (int mf = 0; mf < 4; ++mf)
#pragma unroll
          for (int nf = 0; nf < 4; ++nf)
            acc[mf][nf] = __builtin_amdgcn_mfma_f32_16x16x32_bf16(af[mf], bfr[nf], acc[mf][nf], 0, 0, 0);
      }
      __syncthreads();
    }
    char* ep = smem;
#pragma unroll
    for (int nf = 0; nf < 4; ++nf) {
      int col = wc * 64 + nf * 16 + (lane & 15);
#pragma unroll
      for (int mf = 0; mf < 4; ++mf)
#pragma unroll
        for (int reg = 0; reg < 4; ++reg) {
          int row = wr * 64 + mf * 16 + ((lane >> 4) << 2) + reg;
          int cph = ((col >> 3) ^ (((row >> 2) & 3) << 2));
          *(bf16*)(ep + row * 256 + (cph << 4) + (col & 7) * 2) = (bf16)acc[mf][nf][reg];
        }
    }
    __syncthreads();
    {
      int sl = mb >> 3, mbl = mb & 7;
      bf16* plane = Gi + (size_t)sl * 3145728 + (size_t)(nb >> 3) * 1048576 + (nb & 7) * 128;
#pragma unroll
      for (int p = 0; p < 8; ++p) {
        int idx = p * 256 + tid;
        int row = idx >> 4, c = idx & 15;
        int cph = c ^ (((row >> 2) & 3) << 2);
        bf16x8 v = *(const bf16x8*)(ep + row * 256 + (cph << 4));
        __builtin_nontemporal_store(v, (bf16x8*)(plane + (size_t)(mbl * 128 + row) * 1024 + c * 8));
      }
    }
    return;
  }

  // ------------------------- gammah role -------------------------
  {
    int lbid = bid - gxblocks;
    int cpx = gmblocks >> 3;
    int wg = (lbid & 7) * cpx + (lbid >> 3);
    int nb = wg & 7, mb = wg >> 3;

    const bf16* aA = Dbfs + ((size_t)(mb * 128 + wid * 8 + (lane >> 3))) * 256 + (lane & 7) * 8;
    const bf16* aB = Wgs + (size_t)nb * 4 * 8192 + wid * 512 + lane * 8;

    f32x4 acc[4][4];
#pragma unroll
    for (int a = 0; a < 4; ++a)
#pragma unroll
      for (int b = 0; b < 4; ++b)
#pragma unroll
        for (int q = 0; q < 4; ++q) acc[a][b][q] = 0.f;

#define GM_STAGE(buf, kt)                                                         \
  do {                                                                            \
    _Pragma("unroll")                                                             \
    for (int q = 0; q < 4; ++q)                                                   \
      GLL16(aA + q * (32 * 256) + (kt) * 64, As + (buf) * 16384 + (q * 4 + wid) * 1024); \
    _Pragma("unroll")                                                             \
    for (int q = 0; q < 4; ++q)                                                   \
      GLL16(aB + (size_t)(kt) * 8192 + q * 2048, Bs + (buf) * 16384 + (q * 4 + wid) * 1024); \
  } while (0)

    GM_STAGE(0, 0);
    __syncthreads();
    for (int kt = 0; kt < 4; ++kt) {
      const int cur = kt & 1;
      if (kt < 3) GM_STAGE(cur ^ 1, kt + 1);
#pragma unroll
      for (int kk = 0; kk < 2; ++kk) {
        int kb = kk * 64 + ((lane >> 4) << 4);
        bf16x8 af[4], bfr[4];
#pragma unroll
        for (int mf = 0; mf < 4; ++mf) {
          int row = wr * 64 + mf * 16 + (lane & 15);
          af[mf] = *(const bf16x8*)(As + cur * 16384 + (((row * 128 + kb)) ^ ((row & 7) << 4)));
        }
#pragma unroll
        for (int nf = 0; nf < 4; ++nf) {
          int nl = wc * 64 + nf * 16 + (lane & 15);
          bfr[nf] = *(const bf16x8*)(Bs + cur * 16384 + (((nl * 128 + kb)) ^ ((nl & 7) << 4)));
        }
#pragma unroll
        for (int mf = 0; mf < 4; ++mf)
#pragma unroll
          for (int nf = 0; nf < 4; ++nf)
            acc[mf][nf] = __builtin_amdgcn_mfma_f32_16x16x32_bf16(af[mf], bfr[nf], acc[mf][nf], 0, 0, 0);
      }
      __syncthreads();
    }
    char* ep = smem;
#pragma unroll
    for (int nf = 0; nf < 4; ++nf) {
      int col = wc * 64 + nf * 16 + (lane & 15);
      float bg = b_gh[nb * 128 + col];
#pragma unroll
      for (int mf = 0; mf < 4; ++mf)
#pragma unroll
        for (int reg = 0; reg < 4; ++reg) {
          int row = wr * 64 + mf * 16 + ((lane >> 4) << 2) + reg;
          int cph = ((col >> 3) ^ (((row >> 2) & 3) << 2));
          *(bf16*)(ep + row * 256 + (cph << 4) + (col & 7) * 2) =
              (bf16)__expf(-fmaxf(acc[mf][nf][reg] + bg, 0.f));
        }
    }
    __syncthreads();
#pragma unroll
    for (int p = 0; p < 8; ++p) {
      int idx = p * 256 + tid;
      int row = idx >> 4, c = idx & 15;
      int cph = c ^ (((row >> 2) & 3) << 2);
      bf16x8 v = *(const bf16x8*)(ep + row * 256 + (cph << 4));
      __builtin_nontemporal_store(v, (bf16x8*)(GH + (size_t)(mb * 128 + row) * 1024 + nb * 128 + c * 8));
    }
  }
}

// ---------------------------------------------------------------------------
// step: single-plane i8 h-GEMM (R14 structure); h f32-state now bf16
// ---------------------------------------------------------------------------
__global__ __launch_bounds__(512, 4) void step_kernel(
    const char* __restrict__ hbs, const bf16* __restrict__ hf,
    const char* __restrict__ WcH3, const float* __restrict__ bias4,
    const bf16* __restrict__ gi, const bf16* __restrict__ gh_next, int is_last,
    bf16* __restrict__ hf_next, char* __restrict__ hbs_next) {
  __shared__ char smem[49152];   // A [2][8192] @0, B [2][16384] @16384
  int tid = threadIdx.x, lane = tid & 63, wid = tid >> 6;
  int wr = wid >> 1, wc = wid & 1;
  int wg = ((blockIdx.x & 7) << 6) + (blockIdx.x >> 3);
  int mb = wg & 15, nb = wg >> 4;

  const char* aA = hbs + (size_t)(mb * 64 + (tid >> 3)) * 1024 + (tid & 7) * 16;
  const char* aB = WcH3 + (size_t)nb * 131072 + (tid >> 3) * 128 + (tid & 7) * 16;

  int j = nb * 32 + wc * 16 + (lane & 15);
  bf16  grv[4], gzv[4], gnv[4], ghv[4], hfv[4];
#pragma unroll
  for (int reg = 0; reg < 4; ++reg) {
    int brow = mb * 64 + wr * 16 + ((lane >> 4) << 2) + reg;
    size_t hb_ = (size_t)brow * 1024 + j;
    grv[reg] = gi[hb_];
    gzv[reg] = gi[1048576 + hb_];
    gnv[reg] = gi[2097152 + hb_];
    ghv[reg] = gh_next[hb_];
    hfv[reg] = hf[hb_];
  }

  i32x4 acc[4];
#pragma unroll
  for (int b = 0; b < 4; ++b)
#pragma unroll
    for (int q = 0; q < 4; ++q) acc[b][q] = 0;

#define ST_STAGE(buf, kt)                                                            \
  do {                                                                               \
    GLL16(aA + (kt) * 128,            smem + (buf) * 8192 + wid * 1024);             \
    GLL16(aB + (kt) * 16384,          smem + 16384 + (buf) * 16384 + wid * 1024);    \
    GLL16(aB + (kt) * 16384 + 8192,   smem + 16384 + (buf) * 16384 + 8192 + wid * 1024); \
  } while (0)

  ST_STAGE(0, 0);
  __syncthreads();
  for (int kt = 0; kt < 8; ++kt) {
    const int cur = kt & 1;
    if (kt < 7) ST_STAGE(cur ^ 1, kt + 1);
    const char* Ab = smem + cur * 8192;
    const char* Bb = smem + 16384 + cur * 16384;
#pragma unroll
    for (int kk = 0; kk < 2; ++kk) {
      int kb = kk * 64 + ((lane >> 4) << 4);
      int row = wr * 16 + (lane & 15);
      i32x4 af = *(const i32x4*)(Ab + ((row * 128 + (kb ^ ((row & 7) << 4)))));
      i32x4 bfr[4];
#pragma unroll
      for (int g = 0; g < 4; ++g) {
        int nl = g * 32 + wc * 16 + (lane & 15);
        bfr[g] = *(const i32x4*)(Bb + ((nl * 128 + (kb ^ ((nl & 7) << 4)))));
      }
#pragma unroll
      for (int g = 0; g < 4; ++g)
        acc[g] = __builtin_amdgcn_mfma_i32_16x16x64_i8(af, bfr[g], acc[g], 0, 0, 0);
    }
    __syncthreads();
  }

  const float ISC_RZ = 3.814697265625e-06f;    // 1/(128*2048)
  const float ISC_N  = 1.9073486328125e-06f;   // 1/(128*4096)
  float br = bias4[j], bz = bias4[1024 + j], bn = bias4[2048 + j], bh = bias4[3072 + j];
#pragma unroll
  for (int reg = 0; reg < 4; ++reg) {
    int brow = mb * 64 + wr * 16 + ((lane >> 4) << 2) + reg;
    float pr  = (float)acc[0][reg] * ISC_RZ + (float)grv[reg] + br;
    float pz  = (float)acc[1][reg] * ISC_RZ + (float)gzv[reg] + bz;
    float pin = (float)acc[2][reg] * ISC_N  + (float)gnv[reg] + bn;
    float phn = (float)acc[3][reg] * ISC_N  + bh;
    float r = sigm(pr), z = sigm(pz);
    float nn = tanh_fast(pin + r * phn);
    float hnew = (1.f - z) * nn + z * (float)hfv[reg];
    float gam = is_last ? 1.f : (float)ghv[reg];
    float hd = hnew * gam;
    hf_next[(size_t)brow * 1024 + j] = (bf16)hd;
    int hi8 = __float2int_rn(hd * 128.f);
    hi8 = hi8 > 127 ? 127 : (hi8 < -127 ? -127 : hi8);
    hbs_next[(size_t)brow * 1024 + (j ^ ((brow & 7) << 4))] = (char)hi8;
  }
}

// ---------------------------------------------------------------------------
// classifier + softmax (h is bf16 now)
// ---------------------------------------------------------------------------
__global__ void cls_kernel(const bf16* __restrict__ h, const float* __restrict__ w_cls,
                           const float* __restrict__ b_cls, float* __restrict__ out) {
  int wid = threadIdx.x >> 6, lane = threadIdx.x & 63;
  int b = blockIdx.x * 4 + wid;
  const bf16* hb = h + (size_t)b * 1024;
  float a0 = 0.f, a1 = 0.f;
#pragma unroll
  for (int e = 0; e < 16; ++e) {
    int i = e * 64 + lane;
    float hv = (float)hb[i];
    a0 += hv * w_cls[i];
    a1 += hv * w_cls[1024 + i];
  }
  for (int off = 32; off; off >>= 1) {
    a0 += __shfl_down(a0, off);
    a1 += __shfl_down(a1, off);
  }
  if (lane == 0) {
    float l0 = a0 + b_cls[0], l1 = a1 + b_cls[1];
    float mx = fmaxf(l0, l1);
    float e0 = __expf(l0 - mx), e1 = __expf(l1 - mx);
    float s = e0 + e1;
    out[b * 2]     = e0 / s;
    out[b * 2 + 1] = e1 / s;
  }
}

// ---------------------------------------------------------------------------
extern "C" void kernel_launch(void* const* d_in, const int* in_sizes, int n_in,
                              void* d_out, int out_size, void* d_ws, size_t ws_size,
                              hipStream_t stream) {
  const float* X     = (const float*)d_in[0];
  const float* Msk   = (const float*)d_in[1];
  const float* D     = (const float*)d_in[2];
  const float* Mean  = (const float*)d_in[3];
  const float* L     = (const float*)d_in[4];
  const float* w_gh  = (const float*)d_in[5];
  const float* b_gh  = (const float*)d_in[6];
  const float* w_gx  = (const float*)d_in[7];
  const float* b_gx  = (const float*)d_in[8];
  const float* w_ih  = (const float*)d_in[9];
  const float* w_hh  = (const float*)d_in[10];
  const float* b_ih  = (const float*)d_in[11];
  const float* b_hh  = (const float*)d_in[12];
  const float* w_cls = (const float*)d_in[13];
  const float* b_cls = (const float*)d_in[14];

  char* w = (char*)d_ws;
  bf16*  XRs   = (bf16*)(w);
  bf16*  Dbfs  = (bf16*)(w + 16777216);
  bf16*  GH    = (bf16*)(w + 25690112);
  bf16*  WcX3  = (bf16*)(w + 61341696);
  char*  WcH3  = (char*)(w + 65536000);
  bf16*  Wgs   = (bf16*)(w + 73924608);
  float* bias4 = (float*)(w + 74448896);
  bf16*  hf0   = (bf16*)(w + 74465280);
  bf16*  hf1   = (bf16*)(w + 78659584);
  char*  hb0   = (char*)(w + 82853888);
  char*  hb1   = (char*)(w + 84951040);
  bf16*  Gi    = (bf16*)(w + 87048192);

  size_t base = 87048192;
  int GCH = 16;
  while (GCH > 1 && base + (size_t)GCH * 6291456ull > ws_size) GCH >>= 1;

  bf16*  hfp[2] = {hf0, hf1};
  char*  hbp[2] = {hb0, hb1};

  hipMemsetAsync(hf0, 0, 2097152, stream);
  hipMemsetAsync(hb0, 0, 1048576, stream);
  wprep_kernel<<<23568, 256, 0, stream>>>(w_ih, w_hh, b_ih, b_hh, w_gh, WcH3, WcX3, Wgs, bias4);

  int t = 0;
  for (int c = 0; c < 4; ++c) {
    int nsl = (c < 3) ? 17 : 16;
    prep_kernel<<<nsl * 1024, 256, 0, stream>>>(X, Msk, D, Mean, L, w_gx, b_gx, XRs, Dbfs, c, nsl);
    for (int sub = 0; sub < 16 / GCH; ++sub) {
      int gxblocks = GCH * 192;
      int nsl2 = (sub == 0) ? nsl : 0;
      combo_kernel<<<gxblocks + nsl2 * 64, 256, 0, stream>>>(
          XRs + (size_t)sub * GCH * 524288, WcX3, Gi, gxblocks,
          Dbfs, Wgs, b_gh, GH, nsl2 * 64);
      for (int tl2 = 0; tl2 < GCH; ++tl2, ++t) {
        int tl = sub * GCH + tl2;
        int cur = t & 1, nxt = cur ^ 1;
        step_kernel<<<512, 512, 0, stream>>>(
            hbp[cur], hfp[cur], WcH3, bias4,
            Gi + (size_t)tl2 * 3145728, GH + (size_t)(tl + 1) * 1048576,
            (t == 63) ? 1 : 0, hfp[nxt], hbp[nxt]);
      }
    }
  }
  cls_kernel<<<256, 256, 0, stream>>>(hfp[0], w_cls, b_cls, (float*)d_out);
}